// Round 4
// baseline (5293.329 us; speedup 1.0000x reference)
//
#include <hip/hip_runtime.h>
#include <cmath>

#define V_ 50257
#define D_ 640
#define NL_ 16
#define DF_ 2560
#define R_ 24
#define DG_ 256
#define PLU_ 276
#define PLUP_ 288
#define B_ 4
#define L_ 1024
#define M_ (B_*L_)
#define EPS_ 1e-6f
#define LN_EPS_ 1e-5f

typedef __bf16 bf16x8 __attribute__((ext_vector_type(8)));
typedef float f32x4 __attribute__((ext_vector_type(4)));

__device__ __forceinline__ float gelu_exact(float x) {
    return 0.5f * x * (1.0f + erff(x * 0.70710678118654752f));
}
__device__ __forceinline__ float sigmoid_f(float x) {
    return 1.0f / (1.0f + expf(-x));
}
__device__ __forceinline__ ushort f2b(float f) {
    union { float f; unsigned u; } v; v.f = f;
    unsigned u = v.u;
    return (ushort)((u + 0x7FFFu + ((u >> 16) & 1u)) >> 16);
}
__device__ __forceinline__ float b2f(ushort b) {
    union { unsigned u; float f; } v; v.u = ((unsigned)b) << 16;
    return v.f;
}

#define GLOAD16(gptr, lptr) \
    __builtin_amdgcn_global_load_lds((const __attribute__((address_space(1))) void*)(gptr), \
                                     (__attribute__((address_space(3))) void*)(lptr), 16, 0, 0)

// Bijective XCD-aware block remap (m204): groups consecutive logical tiles on
// one XCD so M-blocks sharing a W-panel hit the same L2.
__device__ __forceinline__ void xcd_remap(int* bm, int* bn, int TM, int TN) {
    const int gx = gridDim.x;
    const int nwg = gx * gridDim.y;
    int d = blockIdx.y * gx + blockIdx.x;
    int q = nwg >> 3, r = nwg & 7;
    int xcd = d & 7, idx = d >> 3;
    int wg = (xcd < r ? xcd * (q + 1) : r * (q + 1) + (xcd - r) * q) + idx;
    *bm = (wg % gx) * TM;
    *bn = (wg / gx) * TN;
}

// LDS layout: row-major [rows][32] bf16 (64B rows), XOR-swizzled: LDS[r][c]
// holds global chunk c ^ ((r>>1)&3) (16B chunks); staging pre-swizzles the
// GLOBAL source (linear LDS dest, m104/m173); ds_read applies the same XOR.

// ---------------------------------------------------------------------------
// 128x128 tile, 4 waves (2x2), each wave 64x64 = 4x4 frags of 16x16x32.
// 2-phase double-buffered pipeline (T3-minimum): STAGE(next) -> ds_read+MFMA
// (cur) -> vmcnt(0) -> s_barrier. One barrier per K-step; load latency hides
// under the MFMA phase.
// EPI: 0 = f32 out; 1 = gelu->bf16 out; 4 = bf16 out
// ---------------------------------------------------------------------------
#define STAGE128(b, k0) do { \
    GLOAD16(A + (size_t)(bm + w * 32 + srow) * (size_t)K + ((k0) + scol), &As[b][(w * 32) * 32]); \
    GLOAD16(A + (size_t)(bm + w * 32 + 16 + srow) * (size_t)K + ((k0) + scol), &As[b][(w * 32 + 16) * 32]); \
    int rb0_ = bn + w * 32 + srow;      if (rb0_ > N - 1) rb0_ = N - 1; \
    int rb1_ = bn + w * 32 + 16 + srow; if (rb1_ > N - 1) rb1_ = N - 1; \
    GLOAD16(W + (size_t)rb0_ * (size_t)K + ((k0) + scol), &Bs[b][(w * 32) * 32]); \
    GLOAD16(W + (size_t)rb1_ * (size_t)K + ((k0) + scol), &Bs[b][(w * 32 + 16) * 32]); \
} while (0)

template<int EPI>
__global__ __launch_bounds__(256) void mgemm128_k(
    const ushort* __restrict__ A, const ushort* __restrict__ W,
    const float* __restrict__ bias, float* __restrict__ Cf,
    ushort* __restrict__ Cb, int M, int N, int K)
{
    __shared__ ushort As[2][128 * 32];
    __shared__ ushort Bs[2][128 * 32];
    const int tid = threadIdx.x;
    const int lane = tid & 63;
    const int w = tid >> 6;
    const int wr = w >> 1, wc = w & 1;
    const int lr = lane & 15, lk = lane >> 4;
    int bm, bn;
    xcd_remap(&bm, &bn, 128, 128);
    const int srow = lane >> 2;
    const int scol = (((lane & 3) ^ ((srow >> 1) & 3)) * 8);

    f32x4 acc[4][4] = {};
    const int nt = K >> 5;

    STAGE128(0, 0);
    asm volatile("s_waitcnt vmcnt(0)" ::: "memory");
    __builtin_amdgcn_s_barrier();

    int cur = 0;
    for (int t = 0; t < nt; ++t) {
        if (t + 1 < nt) { STAGE128(cur ^ 1, (t + 1) * 32); }
        bf16x8 af[4], bfr[4];
        #pragma unroll
        for (int m = 0; m < 4; ++m) {
            int rr = wr * 64 + m * 16 + lr;
            af[m] = *reinterpret_cast<const bf16x8*>(&As[cur][rr * 32 + ((lk ^ ((rr >> 1) & 3)) * 8)]);
        }
        #pragma unroll
        for (int n = 0; n < 4; ++n) {
            int rr = wc * 64 + n * 16 + lr;
            bfr[n] = *reinterpret_cast<const bf16x8*>(&Bs[cur][rr * 32 + ((lk ^ ((rr >> 1) & 3)) * 8)]);
        }
        #pragma unroll
        for (int m = 0; m < 4; ++m)
            #pragma unroll
            for (int n = 0; n < 4; ++n)
                acc[m][n] = __builtin_amdgcn_mfma_f32_16x16x32_bf16(af[m], bfr[n], acc[m][n], 0, 0, 0);
        asm volatile("s_waitcnt vmcnt(0)" ::: "memory");
        __builtin_amdgcn_s_barrier();
        cur ^= 1;
    }

    #pragma unroll
    for (int n = 0; n < 4; ++n) {
        int col = bn + wc * 64 + n * 16 + lr;
        if (col >= N) continue;
        float bsv = bias ? bias[col] : 0.0f;
        #pragma unroll
        for (int m = 0; m < 4; ++m) {
            #pragma unroll
            for (int r4 = 0; r4 < 4; ++r4) {
                int row = bm + wr * 64 + m * 16 + lk * 4 + r4;
                float o = acc[m][n][r4] + bsv;
                size_t idx = (size_t)row * N + col;
                if (EPI == 0)      Cf[idx] = o;
                else if (EPI == 1) Cb[idx] = f2b(gelu_exact(o));
                else if (EPI == 4) Cb[idx] = f2b(o);
            }
        }
    }
}

// ---------------------------------------------------------------------------
// 128x64 tile, 4 waves, each wave 64x32 = 4x2 frags. For N=640 GEMMs (gate,
// fc2) -- 320 blocks instead of 160. Same 2-phase dbuf pipeline.
// EPI==2: alpha = sigmoid(o); Cf(x) += a*h + (1-a)*g. EPI==3: Cf += o.
// ---------------------------------------------------------------------------
#define STAGE12864(b, k0) do { \
    GLOAD16(A + (size_t)(bm + w * 16 + srow) * (size_t)K + ((k0) + scol), &As[b][(w * 16) * 32]); \
    GLOAD16(A + (size_t)(bm + 64 + w * 16 + srow) * (size_t)K + ((k0) + scol), &As[b][(64 + w * 16) * 32]); \
    GLOAD16(W + (size_t)(bn + w * 16 + srow) * (size_t)K + ((k0) + scol), &Bs[b][(w * 16) * 32]); \
} while (0)

template<int EPI>
__global__ __launch_bounds__(256) void mgemm12864_k(
    const ushort* __restrict__ A, const ushort* __restrict__ W,
    const float* __restrict__ bias, float* __restrict__ Cf,
    const float* __restrict__ hbuf, const float* __restrict__ gbuf,
    int M, int N, int K)
{
    __shared__ ushort As[2][128 * 32];
    __shared__ ushort Bs[2][64 * 32];
    const int tid = threadIdx.x;
    const int lane = tid & 63;
    const int w = tid >> 6;
    const int wr = w >> 1, wc = w & 1;
    const int lr = lane & 15, lk = lane >> 4;
    int bm, bn;
    xcd_remap(&bm, &bn, 128, 64);
    const int srow = lane >> 2;
    const int scol = (((lane & 3) ^ ((srow >> 1) & 3)) * 8);

    f32x4 acc[4][2] = {};
    const int nt = K >> 5;

    STAGE12864(0, 0);
    asm volatile("s_waitcnt vmcnt(0)" ::: "memory");
    __builtin_amdgcn_s_barrier();

    int cur = 0;
    for (int t = 0; t < nt; ++t) {
        if (t + 1 < nt) { STAGE12864(cur ^ 1, (t + 1) * 32); }
        bf16x8 af[4], bfr[2];
        #pragma unroll
        for (int m = 0; m < 4; ++m) {
            int rr = wr * 64 + m * 16 + lr;
            af[m] = *reinterpret_cast<const bf16x8*>(&As[cur][rr * 32 + ((lk ^ ((rr >> 1) & 3)) * 8)]);
        }
        #pragma unroll
        for (int n = 0; n < 2; ++n) {
            int rr = wc * 32 + n * 16 + lr;
            bfr[n] = *reinterpret_cast<const bf16x8*>(&Bs[cur][rr * 32 + ((lk ^ ((rr >> 1) & 3)) * 8)]);
        }
        #pragma unroll
        for (int m = 0; m < 4; ++m)
            #pragma unroll
            for (int n = 0; n < 2; ++n)
                acc[m][n] = __builtin_amdgcn_mfma_f32_16x16x32_bf16(af[m], bfr[n], acc[m][n], 0, 0, 0);
        asm volatile("s_waitcnt vmcnt(0)" ::: "memory");
        __builtin_amdgcn_s_barrier();
        cur ^= 1;
    }

    #pragma unroll
    for (int n = 0; n < 2; ++n) {
        int col = bn + wc * 32 + n * 16 + lr;
        float bsv = bias ? bias[col] : 0.0f;
        #pragma unroll
        for (int m = 0; m < 4; ++m) {
            #pragma unroll
            for (int r4 = 0; r4 < 4; ++r4) {
                int row = bm + wr * 64 + m * 16 + lk * 4 + r4;
                float o = acc[m][n][r4] + bsv;
                size_t idx = (size_t)row * N + col;
                if (EPI == 2) {
                    float a = sigmoid_f(o);
                    Cf[idx] = Cf[idx] + a * hbuf[idx] + (1.0f - a) * gbuf[idx];
                } else {
                    Cf[idx] += o;
                }
            }
        }
    }
}

// ---------------------------------------------------------------------------
// red projection: z[M,24] = h[M,640] . redw[24,640]^T + bias.
// 128 blocks x 256 threads; 32 rows/block, 8 col-groups of 3 cols each.
// redw (61 KB) stays L2-resident; h rows broadcast across the 8 col lanes.
// ---------------------------------------------------------------------------
__global__ __launch_bounds__(256) void red_k(
    const float* __restrict__ h, const float* __restrict__ rw,
    const float* __restrict__ rb, float* __restrict__ z)
{
    const int tid = threadIdx.x;
    const int row = blockIdx.x * 32 + (tid >> 3);
    const int cg = tid & 7;
    const float4* h4 = reinterpret_cast<const float4*>(h + (size_t)row * D_);
    const float4* w0 = reinterpret_cast<const float4*>(rw + (size_t)cg * D_);
    const float4* w1 = reinterpret_cast<const float4*>(rw + (size_t)(cg + 8) * D_);
    const float4* w2 = reinterpret_cast<const float4*>(rw + (size_t)(cg + 16) * D_);
    float acc0 = 0.f, acc1 = 0.f, acc2 = 0.f;
    #pragma unroll 4
    for (int k = 0; k < D_ / 4; ++k) {
        float4 hv = h4[k];
        float4 a = w0[k];
        float4 b = w1[k];
        float4 c = w2[k];
        acc0 += hv.x * a.x + hv.y * a.y + hv.z * a.z + hv.w * a.w;
        acc1 += hv.x * b.x + hv.y * b.y + hv.z * b.z + hv.w * b.w;
        acc2 += hv.x * c.x + hv.y * c.y + hv.z * c.z + hv.w * c.w;
    }
    z[(size_t)row * R_ + cg]      = acc0 + rb[cg];
    z[(size_t)row * R_ + cg + 8]  = acc1 + rb[cg + 8];
    z[(size_t)row * R_ + cg + 16] = acc2 + rb[cg + 16];
}

// ---------------------------------------------------------------------------
__global__ __launch_bounds__(256) void embed_k(
    const int* __restrict__ ids, const float* __restrict__ tok,
    const float* __restrict__ pos, float* __restrict__ x)
{
    int idx = blockIdx.x * 256 + threadIdx.x;
    if (idx >= M_ * D_) return;
    int row = idx / D_;
    int d = idx - row * D_;
    int l = row & (L_ - 1);
    x[idx] = tok[(size_t)ids[row] * D_ + d] + pos[(size_t)l * D_ + d];
}

__global__ __launch_bounds__(256) void cvt_k(
    const float* __restrict__ src, ushort* __restrict__ dst, int n)
{
    int idx = blockIdx.x * 256 + threadIdx.x;
    if (idx < n) dst[idx] = f2b(src[idx]);
}

// per-layer weight conversion (gp1 padded 276->288, gp2, gate, fc1, fc2)
#define WC_G1  73728
#define WC_G2  (WC_G1 + 163840)
#define WC_GT  (WC_G2 + 819200)
#define WC_F1  (WC_GT + 1638400)
#define WC_F2  (WC_F1 + 1638400)
__global__ __launch_bounds__(256) void wconv_k(
    const float* __restrict__ g1, const float* __restrict__ g2,
    const float* __restrict__ gt, const float* __restrict__ f1,
    const float* __restrict__ f2, ushort* __restrict__ wb)
{
    int idx = blockIdx.x * 256 + threadIdx.x;
    if (idx < WC_G1) {
        int row = idx / PLUP_, c = idx - row * PLUP_;
        wb[idx] = (c < PLU_) ? f2b(g1[row * PLU_ + c]) : (ushort)0;
    } else if (idx < WC_G2) {
        wb[idx] = f2b(g2[idx - WC_G1]);
    } else if (idx < WC_GT) {
        wb[idx] = f2b(gt[idx - WC_G2]);
    } else if (idx < WC_F1) {
        wb[idx] = f2b(f1[idx - WC_GT]);
    } else if (idx < WC_F2) {
        wb[idx] = f2b(f2[idx - WC_F1]);
    }
}

// ---------------------------------------------------------------------------
__global__ __launch_bounds__(128) void ln_k(
    const float* __restrict__ x, const float* __restrict__ w,
    const float* __restrict__ b, float* __restrict__ outf,
    ushort* __restrict__ outb, int bstride)
{
    int row = blockIdx.x;
    int tid = threadIdx.x;
    const float* xr = x + (size_t)row * D_;
    float v[5];
    float sum = 0.f, sumsq = 0.f;
    #pragma unroll
    for (int t = 0; t < 5; ++t) {
        v[t] = xr[tid + t * 128];
        sum += v[t]; sumsq += v[t] * v[t];
    }
    #pragma unroll
    for (int off = 32; off > 0; off >>= 1) {
        sum += __shfl_down(sum, off);
        sumsq += __shfl_down(sumsq, off);
    }
    __shared__ float s0[2], s1[2];
    if ((tid & 63) == 0) { s0[tid >> 6] = sum; s1[tid >> 6] = sumsq; }
    __syncthreads();
    float m = (s0[0] + s0[1]) * (1.0f / D_);
    float var = (s1[0] + s1[1]) * (1.0f / D_) - m * m;
    float inv = rsqrtf(var + LN_EPS_);
    #pragma unroll
    for (int t = 0; t < 5; ++t) {
        int d = tid + t * 128;
        float o = (v[t] - m) * inv * w[d] + b[d];
        if (outf) outf[(size_t)row * D_ + d] = o;
        if (outb) outb[(size_t)row * bstride + d] = f2b(o);
    }
}

// ---------------------------------------------------------------------------
__global__ __launch_bounds__(128) void plucker7_k(
    const float* __restrict__ z, ushort* __restrict__ pb)
{
    int oi = blockIdx.y;
    int delta = 1 << oi;
    int row = blockIdx.x;
    int l = row & (L_ - 1);
    int tid = threadIdx.x;
    ushort* out = pb + ((size_t)oi * M_ + row) * PLUP_;
    if (l < delta) {
        for (int idx = tid; idx < PLUP_; idx += 128) out[idx] = 0;
        return;
    }
    __shared__ float zc[R_], zp[R_];
    if (tid < R_) {
        zc[tid] = z[(size_t)row * R_ + tid];
        zp[tid] = z[(size_t)(row - delta) * R_ + tid];
    }
    __syncthreads();
    float vals[3];
    float ss = 0.f;
    #pragma unroll
    for (int t = 0; t < 3; ++t) {
        int idx = tid + t * 128;
        float val = 0.f;
        if (idx < PLU_) {
            int i = 0, rem = idx;
            while (rem >= 23 - i) { rem -= 23 - i; ++i; }
            int j = i + 1 + rem;
            val = zp[i] * zc[j] - zp[j] * zc[i];
        }
        vals[t] = val;
        ss += val * val;
    }
    #pragma unroll
    for (int off = 32; off > 0; off >>= 1) ss += __shfl_down(ss, off);
    __shared__ float wsum[2];
    if ((tid & 63) == 0) wsum[tid >> 6] = ss;
    __syncthreads();
    float inv = 1.0f / fmaxf(sqrtf(wsum[0] + wsum[1]), EPS_);
    #pragma unroll
    for (int t = 0; t < 3; ++t) {
        int idx = tid + t * 128;
        if (idx < PLUP_) out[idx] = (idx < PLU_) ? f2b(vals[t] * inv) : (ushort)0;
    }
}

// ---------------------------------------------------------------------------
__global__ __launch_bounds__(256) void greduce_k(
    const ushort* __restrict__ gbigb, float* __restrict__ g,
    ushort* __restrict__ hgb)
{
    int idx = blockIdx.x * 256 + threadIdx.x;
    if (idx >= M_ * D_) return;
    int row = idx / D_;
    int d = idx - row * D_;
    int l = row & (L_ - 1);
    float s = 0.f;
    int c = 0;
    #pragma unroll
    for (int oi = 0; oi < 7; ++oi) {
        if (l >= (1 << oi)) {
            s += b2f(gbigb[(size_t)oi * M_ * D_ + idx]);
            ++c;
        }
    }
    float gv = s / (float)max(c, 1);
    g[idx] = gv;
    hgb[(size_t)row * (2 * D_) + D_ + d] = f2b(gv);
}

// ---------------------------------------------------------------------------
static void mg128(int epi, const ushort* A, const ushort* W, const float* bias,
                  float* Cf, ushort* Cb, int M, int N, int K, hipStream_t s)
{
    dim3 grid(M / 128, (N + 127) / 128), block(256);
    if (epi == 0)      mgemm128_k<0><<<grid, block, 0, s>>>(A, W, bias, Cf, Cb, M, N, K);
    else if (epi == 1) mgemm128_k<1><<<grid, block, 0, s>>>(A, W, bias, Cf, Cb, M, N, K);
    else               mgemm128_k<4><<<grid, block, 0, s>>>(A, W, bias, Cf, Cb, M, N, K);
}

static void mg12864(int epi, const ushort* A, const ushort* W, const float* bias,
                    float* Cf, const float* h, const float* g, int M, int N, int K,
                    hipStream_t s)
{
    dim3 grid(M / 128, N / 64), block(256);
    if (epi == 2) mgemm12864_k<2><<<grid, block, 0, s>>>(A, W, bias, Cf, h, g, M, N, K);
    else          mgemm12864_k<3><<<grid, block, 0, s>>>(A, W, bias, Cf, h, g, M, N, K);
}

extern "C" void kernel_launch(void* const* d_in, const int* in_sizes, int n_in,
                              void* d_out, int out_size, void* d_ws, size_t ws_size,
                              hipStream_t stream)
{
    const int*   ids   = (const int*)d_in[0];
    const float* tok   = (const float*)d_in[1];
    const float* pos   = (const float*)d_in[2];
    const float* ln1w  = (const float*)d_in[3];
    const float* ln1b  = (const float*)d_in[4];
    const float* redw  = (const float*)d_in[5];
    const float* redb  = (const float*)d_in[6];
    const float* gp1w  = (const float*)d_in[7];
    const float* gp1b  = (const float*)d_in[8];
    const float* gp2w  = (const float*)d_in[9];
    const float* gp2b  = (const float*)d_in[10];
    const float* gatew = (const float*)d_in[11];
    const float* gateb = (const float*)d_in[12];
    const float* ln2w  = (const float*)d_in[13];
    const float* ln2b  = (const float*)d_in[14];
    const float* fc1w  = (const float*)d_in[15];
    const float* fc1b  = (const float*)d_in[16];
    const float* fc2w  = (const float*)d_in[17];
    const float* fc2b  = (const float*)d_in[18];
    const float* fnw   = (const float*)d_in[19];
    const float* fnb   = (const float*)d_in[20];
    float* out = (float*)d_out;

    const size_t MD = (size_t)M_ * D_;
    float* ws = (float*)d_ws;
    float* x = ws;                       // MD
    float* h = x + MD;                   // MD
    float* g = h + MD;                   // MD
    float* z = g + MD;                   // M_*R_
    ushort* gbigb = (ushort*)(z + (size_t)M_ * R_);       // 7*MD
    ushort* pb    = gbigb + 7 * MD;                       // 7*M_*288
    ushort* c1b   = pb + (size_t)7 * M_ * PLUP_;          // 7*M_*256
    ushort* hgb   = c1b + (size_t)7 * M_ * DG_;           // M_*1280
    ushort* h2b   = hgb + (size_t)M_ * 2 * D_;            // M_*640
    ushort* ffb   = h2b + MD;                             // M_*2560
    ushort* xnb   = ffb + (size_t)M_ * DF_;               // M_*640
    ushort* tokb  = xnb + MD;                             // V_*640
    ushort* wb    = tokb + (size_t)V_ * D_;               // 4,333,568

    const int ELT_GRID = (M_ * D_ + 255) / 256;

    embed_k<<<ELT_GRID, 256, 0, stream>>>(ids, tok, pos, x);
    cvt_k<<<(V_ * D_ + 255) / 256, 256, 0, stream>>>(tok, tokb, V_ * D_);

    for (int l = 0; l < NL_; ++l) {
        wconv_k<<<(WC_F2 + 255) / 256, 256, 0, stream>>>(
            gp1w + (size_t)l * DG_ * PLU_, gp2w + (size_t)l * D_ * DG_,
            gatew + (size_t)l * D_ * 2 * D_, fc1w + (size_t)l * DF_ * D_,
            fc2w + (size_t)l * D_ * DF_, wb);
        ln_k<<<M_, 128, 0, stream>>>(x, ln1w + (size_t)l * D_, ln1b + (size_t)l * D_,
                                     h, hgb, 2 * D_);
        red_k<<<M_ / 32, 256, 0, stream>>>(h, redw + (size_t)l * R_ * D_,
                                           redb + (size_t)l * R_, z);
        plucker7_k<<<dim3(M_, 7), 128, 0, stream>>>(z, pb);
        mg128(1, pb, wb, gp1b + (size_t)l * DG_, nullptr, c1b, 7 * M_, DG_, PLUP_, stream);
        mg128(4, c1b, wb + WC_G1, gp2b + (size_t)l * D_, nullptr, gbigb, 7 * M_, D_, DG_, stream);
        greduce_k<<<ELT_GRID, 256, 0, stream>>>(gbigb, g, hgb);
        // gate GEMM fused with x-update: x = x + a*h + (1-a)*g
        mg12864(2, hgb, wb + WC_G2, gateb + (size_t)l * D_, x, h, g, M_, D_, 2 * D_, stream);
        ln_k<<<M_, 128, 0, stream>>>(x, ln2w + (size_t)l * D_, ln2b + (size_t)l * D_,
                                     nullptr, h2b, D_);
        mg128(1, h2b, wb + WC_GT, fc1b + (size_t)l * DF_, nullptr, ffb, M_, DF_, D_, stream);
        mg12864(3, ffb, wb + WC_F1, fc2b + (size_t)l * D_, x, nullptr, nullptr, M_, D_, DF_, stream);
    }
    ln_k<<<M_, 128, 0, stream>>>(x, fnw, fnb, nullptr, xnb, D_);
    mg128(0, xnb, tokb, nullptr, out, nullptr, M_, V_, D_, stream);
}

// Round 5
// 5109.879 us; speedup vs baseline: 1.0359x; 1.0359x over previous
//
#include <hip/hip_runtime.h>
#include <cmath>

#define V_ 50257
#define D_ 640
#define NL_ 16
#define DF_ 2560
#define R_ 24
#define DG_ 256
#define PLU_ 276
#define PLUP_ 288
#define B_ 4
#define L_ 1024
#define M_ (B_*L_)
#define EPS_ 1e-6f
#define LN_EPS_ 1e-5f

typedef __bf16 bf16x8 __attribute__((ext_vector_type(8)));
typedef float f32x4 __attribute__((ext_vector_type(4)));

__device__ __forceinline__ float gelu_exact(float x) {
    return 0.5f * x * (1.0f + erff(x * 0.70710678118654752f));
}
__device__ __forceinline__ float sigmoid_f(float x) {
    return 1.0f / (1.0f + expf(-x));
}
__device__ __forceinline__ ushort f2b(float f) {
    union { float f; unsigned u; } v; v.f = f;
    unsigned u = v.u;
    return (ushort)((u + 0x7FFFu + ((u >> 16) & 1u)) >> 16);
}
__device__ __forceinline__ float b2f(ushort b) {
    union { unsigned u; float f; } v; v.u = ((unsigned)b) << 16;
    return v.f;
}

#define GLOAD16(gptr, lptr) \
    __builtin_amdgcn_global_load_lds((const __attribute__((address_space(1))) void*)(gptr), \
                                     (__attribute__((address_space(3))) void*)(lptr), 16, 0, 0)

// NOTE (R4 post-mortem): XCD-aware remap (m204) REGRESSED here -- lm_head
// FETCH_SIZE 288MB -> 830MB. The d%8=XCD dispatch assumption doesn't hold for
// this harness's 2D grids. Natural order (blockIdx.x = M-block, fastest) is
// the measured-best mapping; do not re-add the remap without an A/B.

// LDS layout: row-major [rows][32] bf16 (64B rows), XOR-swizzled: LDS[r][c]
// holds global chunk c ^ ((r>>1)&3) (16B chunks); staging pre-swizzles the
// GLOBAL source (linear LDS dest, m104/m173); ds_read applies the same XOR.
// Measured: SQ_LDS_BANK_CONFLICT 3.2e7 -> 0 (R2->R3).

// ---------------------------------------------------------------------------
// 128x128 tile, 4 waves (2x2), each wave 64x64 = 4x4 frags of 16x16x32.
// 2-phase double-buffered pipeline (T3-minimum): STAGE(next) -> ds_read+MFMA
// (cur) -> vmcnt(0) -> s_barrier. Measured: lm_head sustained BW 2653 -> 3500
// GB/s with this pipeline (R4).
// EPI: 0 = f32 out; 1 = gelu->bf16 out; 4 = bf16 out
// ---------------------------------------------------------------------------
#define STAGE128(b, k0) do { \
    GLOAD16(A + (size_t)(bm + w * 32 + srow) * (size_t)K + ((k0) + scol), &As[b][(w * 32) * 32]); \
    GLOAD16(A + (size_t)(bm + w * 32 + 16 + srow) * (size_t)K + ((k0) + scol), &As[b][(w * 32 + 16) * 32]); \
    int rb0_ = bn + w * 32 + srow;      if (rb0_ > N - 1) rb0_ = N - 1; \
    int rb1_ = bn + w * 32 + 16 + srow; if (rb1_ > N - 1) rb1_ = N - 1; \
    GLOAD16(W + (size_t)rb0_ * (size_t)K + ((k0) + scol), &Bs[b][(w * 32) * 32]); \
    GLOAD16(W + (size_t)rb1_ * (size_t)K + ((k0) + scol), &Bs[b][(w * 32 + 16) * 32]); \
} while (0)

template<int EPI>
__global__ __launch_bounds__(256) void mgemm128_k(
    const ushort* __restrict__ A, const ushort* __restrict__ W,
    const float* __restrict__ bias, float* __restrict__ Cf,
    ushort* __restrict__ Cb, int M, int N, int K)
{
    __shared__ ushort As[2][128 * 32];
    __shared__ ushort Bs[2][128 * 32];
    const int tid = threadIdx.x;
    const int lane = tid & 63;
    const int w = tid >> 6;
    const int wr = w >> 1, wc = w & 1;
    const int lr = lane & 15, lk = lane >> 4;
    const int bm = blockIdx.x * 128, bn = blockIdx.y * 128;
    const int srow = lane >> 2;
    const int scol = (((lane & 3) ^ ((srow >> 1) & 3)) * 8);

    f32x4 acc[4][4] = {};
    const int nt = K >> 5;

    STAGE128(0, 0);
    asm volatile("s_waitcnt vmcnt(0)" ::: "memory");
    __builtin_amdgcn_s_barrier();

    int cur = 0;
    for (int t = 0; t < nt; ++t) {
        if (t + 1 < nt) { STAGE128(cur ^ 1, (t + 1) * 32); }
        bf16x8 af[4], bfr[4];
        #pragma unroll
        for (int m = 0; m < 4; ++m) {
            int rr = wr * 64 + m * 16 + lr;
            af[m] = *reinterpret_cast<const bf16x8*>(&As[cur][rr * 32 + ((lk ^ ((rr >> 1) & 3)) * 8)]);
        }
        #pragma unroll
        for (int n = 0; n < 4; ++n) {
            int rr = wc * 64 + n * 16 + lr;
            bfr[n] = *reinterpret_cast<const bf16x8*>(&Bs[cur][rr * 32 + ((lk ^ ((rr >> 1) & 3)) * 8)]);
        }
        #pragma unroll
        for (int m = 0; m < 4; ++m)
            #pragma unroll
            for (int n = 0; n < 4; ++n)
                acc[m][n] = __builtin_amdgcn_mfma_f32_16x16x32_bf16(af[m], bfr[n], acc[m][n], 0, 0, 0);
        asm volatile("s_waitcnt vmcnt(0)" ::: "memory");
        __builtin_amdgcn_s_barrier();
        cur ^= 1;
    }

    #pragma unroll
    for (int n = 0; n < 4; ++n) {
        int col = bn + wc * 64 + n * 16 + lr;
        if (col >= N) continue;
        float bsv = bias ? bias[col] : 0.0f;
        #pragma unroll
        for (int m = 0; m < 4; ++m) {
            #pragma unroll
            for (int r4 = 0; r4 < 4; ++r4) {
                int row = bm + wr * 64 + m * 16 + lk * 4 + r4;
                float o = acc[m][n][r4] + bsv;
                size_t idx = (size_t)row * N + col;
                if (EPI == 0)      Cf[idx] = o;
                else if (EPI == 1) Cb[idx] = f2b(gelu_exact(o));
                else if (EPI == 4) Cb[idx] = f2b(o);
            }
        }
    }
}

// ---------------------------------------------------------------------------
// 128x64 tile, 4 waves, each wave 64x32 = 4x2 frags. For N=640 GEMMs (gate,
// fc2) -- 320 blocks instead of 160. Same 2-phase dbuf pipeline.
// EPI==2: alpha = sigmoid(o); Cf(x) += a*h + (1-a)*g. EPI==3: Cf += o.
// ---------------------------------------------------------------------------
#define STAGE12864(b, k0) do { \
    GLOAD16(A + (size_t)(bm + w * 16 + srow) * (size_t)K + ((k0) + scol), &As[b][(w * 16) * 32]); \
    GLOAD16(A + (size_t)(bm + 64 + w * 16 + srow) * (size_t)K + ((k0) + scol), &As[b][(64 + w * 16) * 32]); \
    GLOAD16(W + (size_t)(bn + w * 16 + srow) * (size_t)K + ((k0) + scol), &Bs[b][(w * 16) * 32]); \
} while (0)

template<int EPI>
__global__ __launch_bounds__(256) void mgemm12864_k(
    const ushort* __restrict__ A, const ushort* __restrict__ W,
    const float* __restrict__ bias, float* __restrict__ Cf,
    const float* __restrict__ hbuf, const float* __restrict__ gbuf,
    int M, int N, int K)
{
    __shared__ ushort As[2][128 * 32];
    __shared__ ushort Bs[2][64 * 32];
    const int tid = threadIdx.x;
    const int lane = tid & 63;
    const int w = tid >> 6;
    const int wr = w >> 1, wc = w & 1;
    const int lr = lane & 15, lk = lane >> 4;
    const int bm = blockIdx.x * 128, bn = blockIdx.y * 64;
    const int srow = lane >> 2;
    const int scol = (((lane & 3) ^ ((srow >> 1) & 3)) * 8);

    f32x4 acc[4][2] = {};
    const int nt = K >> 5;

    STAGE12864(0, 0);
    asm volatile("s_waitcnt vmcnt(0)" ::: "memory");
    __builtin_amdgcn_s_barrier();

    int cur = 0;
    for (int t = 0; t < nt; ++t) {
        if (t + 1 < nt) { STAGE12864(cur ^ 1, (t + 1) * 32); }
        bf16x8 af[4], bfr[2];
        #pragma unroll
        for (int m = 0; m < 4; ++m) {
            int rr = wr * 64 + m * 16 + lr;
            af[m] = *reinterpret_cast<const bf16x8*>(&As[cur][rr * 32 + ((lk ^ ((rr >> 1) & 3)) * 8)]);
        }
        #pragma unroll
        for (int n = 0; n < 2; ++n) {
            int rr = wc * 32 + n * 16 + lr;
            bfr[n] = *reinterpret_cast<const bf16x8*>(&Bs[cur][rr * 32 + ((lk ^ ((rr >> 1) & 3)) * 8)]);
        }
        #pragma unroll
        for (int m = 0; m < 4; ++m)
            #pragma unroll
            for (int n = 0; n < 2; ++n)
                acc[m][n] = __builtin_amdgcn_mfma_f32_16x16x32_bf16(af[m], bfr[n], acc[m][n], 0, 0, 0);
        asm volatile("s_waitcnt vmcnt(0)" ::: "memory");
        __builtin_amdgcn_s_barrier();
        cur ^= 1;
    }

    #pragma unroll
    for (int n = 0; n < 2; ++n) {
        int col = bn + wc * 32 + n * 16 + lr;
        float bsv = bias ? bias[col] : 0.0f;
        #pragma unroll
        for (int m = 0; m < 4; ++m) {
            #pragma unroll
            for (int r4 = 0; r4 < 4; ++r4) {
                int row = bm + wr * 64 + m * 16 + lk * 4 + r4;
                float o = acc[m][n][r4] + bsv;
                size_t idx = (size_t)row * N + col;
                if (EPI == 2) {
                    float a = sigmoid_f(o);
                    Cf[idx] = Cf[idx] + a * hbuf[idx] + (1.0f - a) * gbuf[idx];
                } else {
                    Cf[idx] += o;
                }
            }
        }
    }
}

// ---------------------------------------------------------------------------
// red projection: z[M,24] = h[M,640] . redw[24,640]^T + bias.
// ---------------------------------------------------------------------------
__global__ __launch_bounds__(256) void red_k(
    const float* __restrict__ h, const float* __restrict__ rw,
    const float* __restrict__ rb, float* __restrict__ z)
{
    const int tid = threadIdx.x;
    const int row = blockIdx.x * 32 + (tid >> 3);
    const int cg = tid & 7;
    const float4* h4 = reinterpret_cast<const float4*>(h + (size_t)row * D_);
    const float4* w0 = reinterpret_cast<const float4*>(rw + (size_t)cg * D_);
    const float4* w1 = reinterpret_cast<const float4*>(rw + (size_t)(cg + 8) * D_);
    const float4* w2 = reinterpret_cast<const float4*>(rw + (size_t)(cg + 16) * D_);
    float acc0 = 0.f, acc1 = 0.f, acc2 = 0.f;
    #pragma unroll 4
    for (int k = 0; k < D_ / 4; ++k) {
        float4 hv = h4[k];
        float4 a = w0[k];
        float4 b = w1[k];
        float4 c = w2[k];
        acc0 += hv.x * a.x + hv.y * a.y + hv.z * a.z + hv.w * a.w;
        acc1 += hv.x * b.x + hv.y * b.y + hv.z * b.z + hv.w * b.w;
        acc2 += hv.x * c.x + hv.y * c.y + hv.z * c.z + hv.w * c.w;
    }
    z[(size_t)row * R_ + cg]      = acc0 + rb[cg];
    z[(size_t)row * R_ + cg + 8]  = acc1 + rb[cg + 8];
    z[(size_t)row * R_ + cg + 16] = acc2 + rb[cg + 16];
}

// ---------------------------------------------------------------------------
__global__ __launch_bounds__(256) void embed_k(
    const int* __restrict__ ids, const float* __restrict__ tok,
    const float* __restrict__ pos, float* __restrict__ x)
{
    int idx = blockIdx.x * 256 + threadIdx.x;
    if (idx >= M_ * D_) return;
    int row = idx / D_;
    int d = idx - row * D_;
    int l = row & (L_ - 1);
    x[idx] = tok[(size_t)ids[row] * D_ + d] + pos[(size_t)l * D_ + d];
}

__global__ __launch_bounds__(256) void cvt_k(
    const float* __restrict__ src, ushort* __restrict__ dst, int n)
{
    int idx = blockIdx.x * 256 + threadIdx.x;
    if (idx < n) dst[idx] = f2b(src[idx]);
}

// per-layer weight conversion (gp1 padded 276->288, gp2, gate, fc1, fc2)
#define WC_G1  73728
#define WC_G2  (WC_G1 + 163840)
#define WC_GT  (WC_G2 + 819200)
#define WC_F1  (WC_GT + 1638400)
#define WC_F2  (WC_F1 + 1638400)
__global__ __launch_bounds__(256) void wconv_k(
    const float* __restrict__ g1, const float* __restrict__ g2,
    const float* __restrict__ gt, const float* __restrict__ f1,
    const float* __restrict__ f2, ushort* __restrict__ wb)
{
    int idx = blockIdx.x * 256 + threadIdx.x;
    if (idx < WC_G1) {
        int row = idx / PLUP_, c = idx - row * PLUP_;
        wb[idx] = (c < PLU_) ? f2b(g1[row * PLU_ + c]) : (ushort)0;
    } else if (idx < WC_G2) {
        wb[idx] = f2b(g2[idx - WC_G1]);
    } else if (idx < WC_GT) {
        wb[idx] = f2b(gt[idx - WC_G2]);
    } else if (idx < WC_F1) {
        wb[idx] = f2b(f1[idx - WC_GT]);
    } else if (idx < WC_F2) {
        wb[idx] = f2b(f2[idx - WC_F1]);
    }
}

// ---------------------------------------------------------------------------
__global__ __launch_bounds__(128) void ln_k(
    const float* __restrict__ x, const float* __restrict__ w,
    const float* __restrict__ b, float* __restrict__ outf,
    ushort* __restrict__ outb, int bstride)
{
    int row = blockIdx.x;
    int tid = threadIdx.x;
    const float* xr = x + (size_t)row * D_;
    float v[5];
    float sum = 0.f, sumsq = 0.f;
    #pragma unroll
    for (int t = 0; t < 5; ++t) {
        v[t] = xr[tid + t * 128];
        sum += v[t]; sumsq += v[t] * v[t];
    }
    #pragma unroll
    for (int off = 32; off > 0; off >>= 1) {
        sum += __shfl_down(sum, off);
        sumsq += __shfl_down(sumsq, off);
    }
    __shared__ float s0[2], s1[2];
    if ((tid & 63) == 0) { s0[tid >> 6] = sum; s1[tid >> 6] = sumsq; }
    __syncthreads();
    float m = (s0[0] + s0[1]) * (1.0f / D_);
    float var = (s1[0] + s1[1]) * (1.0f / D_) - m * m;
    float inv = rsqrtf(var + LN_EPS_);
    #pragma unroll
    for (int t = 0; t < 5; ++t) {
        int d = tid + t * 128;
        float o = (v[t] - m) * inv * w[d] + b[d];
        if (outf) outf[(size_t)row * D_ + d] = o;
        if (outb) outb[(size_t)row * bstride + d] = f2b(o);
    }
}

// ---------------------------------------------------------------------------
__global__ __launch_bounds__(128) void plucker7_k(
    const float* __restrict__ z, ushort* __restrict__ pb)
{
    int oi = blockIdx.y;
    int delta = 1 << oi;
    int row = blockIdx.x;
    int l = row & (L_ - 1);
    int tid = threadIdx.x;
    ushort* out = pb + ((size_t)oi * M_ + row) * PLUP_;
    if (l < delta) {
        for (int idx = tid; idx < PLUP_; idx += 128) out[idx] = 0;
        return;
    }
    __shared__ float zc[R_], zp[R_];
    if (tid < R_) {
        zc[tid] = z[(size_t)row * R_ + tid];
        zp[tid] = z[(size_t)(row - delta) * R_ + tid];
    }
    __syncthreads();
    float vals[3];
    float ss = 0.f;
    #pragma unroll
    for (int t = 0; t < 3; ++t) {
        int idx = tid + t * 128;
        float val = 0.f;
        if (idx < PLU_) {
            int i = 0, rem = idx;
            while (rem >= 23 - i) { rem -= 23 - i; ++i; }
            int j = i + 1 + rem;
            val = zp[i] * zc[j] - zp[j] * zc[i];
        }
        vals[t] = val;
        ss += val * val;
    }
    #pragma unroll
    for (int off = 32; off > 0; off >>= 1) ss += __shfl_down(ss, off);
    __shared__ float wsum[2];
    if ((tid & 63) == 0) wsum[tid >> 6] = ss;
    __syncthreads();
    float inv = 1.0f / fmaxf(sqrtf(wsum[0] + wsum[1]), EPS_);
    #pragma unroll
    for (int t = 0; t < 3; ++t) {
        int idx = tid + t * 128;
        if (idx < PLUP_) out[idx] = (idx < PLU_) ? f2b(vals[t] * inv) : (ushort)0;
    }
}

// ---------------------------------------------------------------------------
__global__ __launch_bounds__(256) void greduce_k(
    const ushort* __restrict__ gbigb, float* __restrict__ g,
    ushort* __restrict__ hgb)
{
    int idx = blockIdx.x * 256 + threadIdx.x;
    if (idx >= M_ * D_) return;
    int row = idx / D_;
    int d = idx - row * D_;
    int l = row & (L_ - 1);
    float s = 0.f;
    int c = 0;
    #pragma unroll
    for (int oi = 0; oi < 7; ++oi) {
        if (l >= (1 << oi)) {
            s += b2f(gbigb[(size_t)oi * M_ * D_ + idx]);
            ++c;
        }
    }
    float gv = s / (float)max(c, 1);
    g[idx] = gv;
    hgb[(size_t)row * (2 * D_) + D_ + d] = f2b(gv);
}

// ---------------------------------------------------------------------------
static void mg128(int epi, const ushort* A, const ushort* W, const float* bias,
                  float* Cf, ushort* Cb, int M, int N, int K, hipStream_t s)
{
    dim3 grid(M / 128, (N + 127) / 128), block(256);
    if (epi == 0)      mgemm128_k<0><<<grid, block, 0, s>>>(A, W, bias, Cf, Cb, M, N, K);
    else if (epi == 1) mgemm128_k<1><<<grid, block, 0, s>>>(A, W, bias, Cf, Cb, M, N, K);
    else               mgemm128_k<4><<<grid, block, 0, s>>>(A, W, bias, Cf, Cb, M, N, K);
}

static void mg12864(int epi, const ushort* A, const ushort* W, const float* bias,
                    float* Cf, const float* h, const float* g, int M, int N, int K,
                    hipStream_t s)
{
    dim3 grid(M / 128, N / 64), block(256);
    if (epi == 2) mgemm12864_k<2><<<grid, block, 0, s>>>(A, W, bias, Cf, h, g, M, N, K);
    else          mgemm12864_k<3><<<grid, block, 0, s>>>(A, W, bias, Cf, h, g, M, N, K);
}

extern "C" void kernel_launch(void* const* d_in, const int* in_sizes, int n_in,
                              void* d_out, int out_size, void* d_ws, size_t ws_size,
                              hipStream_t stream)
{
    const int*   ids   = (const int*)d_in[0];
    const float* tok   = (const float*)d_in[1];
    const float* pos   = (const float*)d_in[2];
    const float* ln1w  = (const float*)d_in[3];
    const float* ln1b  = (const float*)d_in[4];
    const float* redw  = (const float*)d_in[5];
    const float* redb  = (const float*)d_in[6];
    const float* gp1w  = (const float*)d_in[7];
    const float* gp1b  = (const float*)d_in[8];
    const float* gp2w  = (const float*)d_in[9];
    const float* gp2b  = (const float*)d_in[10];
    const float* gatew = (const float*)d_in[11];
    const float* gateb = (const float*)d_in[12];
    const float* ln2w  = (const float*)d_in[13];
    const float* ln2b  = (const float*)d_in[14];
    const float* fc1w  = (const float*)d_in[15];
    const float* fc1b  = (const float*)d_in[16];
    const float* fc2w  = (const float*)d_in[17];
    const float* fc2b  = (const float*)d_in[18];
    const float* fnw   = (const float*)d_in[19];
    const float* fnb   = (const float*)d_in[20];
    float* out = (float*)d_out;

    const size_t MD = (size_t)M_ * D_;
    float* ws = (float*)d_ws;
    float* x = ws;                       // MD
    float* h = x + MD;                   // MD
    float* g = h + MD;                   // MD
    float* z = g + MD;                   // M_*R_
    ushort* gbigb = (ushort*)(z + (size_t)M_ * R_);       // 7*MD
    ushort* pb    = gbigb + 7 * MD;                       // 7*M_*288
    ushort* c1b   = pb + (size_t)7 * M_ * PLUP_;          // 7*M_*256
    ushort* hgb   = c1b + (size_t)7 * M_ * DG_;           // M_*1280
    ushort* h2b   = hgb + (size_t)M_ * 2 * D_;            // M_*640
    ushort* ffb   = h2b + MD;                             // M_*2560
    ushort* xnb   = ffb + (size_t)M_ * DF_;               // M_*640
    ushort* tokb  = xnb + MD;                             // V_*640
    ushort* wb    = tokb + (size_t)V_ * D_;               // 4,333,568

    const int ELT_GRID = (M_ * D_ + 255) / 256;

    embed_k<<<ELT_GRID, 256, 0, stream>>>(ids, tok, pos, x);
    cvt_k<<<(V_ * D_ + 255) / 256, 256, 0, stream>>>(tok, tokb, V_ * D_);

    for (int l = 0; l < NL_; ++l) {
        wconv_k<<<(WC_F2 + 255) / 256, 256, 0, stream>>>(
            gp1w + (size_t)l * DG_ * PLU_, gp2w + (size_t)l * D_ * DG_,
            gatew + (size_t)l * D_ * 2 * D_, fc1w + (size_t)l * DF_ * D_,
            fc2w + (size_t)l * D_ * DF_, wb);
        ln_k<<<M_, 128, 0, stream>>>(x, ln1w + (size_t)l * D_, ln1b + (size_t)l * D_,
                                     h, hgb, 2 * D_);
        red_k<<<M_ / 32, 256, 0, stream>>>(h, redw + (size_t)l * R_ * D_,
                                           redb + (size_t)l * R_, z);
        plucker7_k<<<dim3(M_, 7), 128, 0, stream>>>(z, pb);
        mg128(1, pb, wb, gp1b + (size_t)l * DG_, nullptr, c1b, 7 * M_, DG_, PLUP_, stream);
        mg128(4, c1b, wb + WC_G1, gp2b + (size_t)l * D_, nullptr, gbigb, 7 * M_, D_, DG_, stream);
        greduce_k<<<ELT_GRID, 256, 0, stream>>>(gbigb, g, hgb);
        // gate GEMM fused with x-update: x = x + a*h + (1-a)*g
        mg12864(2, hgb, wb + WC_G2, gateb + (size_t)l * D_, x, h, g, M_, D_, 2 * D_, stream);
        ln_k<<<M_, 128, 0, stream>>>(x, ln2w + (size_t)l * D_, ln2b + (size_t)l * D_,
                                     nullptr, h2b, D_);
        mg128(1, h2b, wb + WC_GT, fc1b + (size_t)l * DF_, nullptr, ffb, M_, DF_, D_, stream);
        mg12864(3, ffb, wb + WC_F1, fc2b + (size_t)l * D_, x, nullptr, nullptr, M_, D_, DF_, stream);
    }
    ln_k<<<M_, 128, 0, stream>>>(x, fnw, fnb, nullptr, xnb, D_);
    mg128(0, xnb, tokb, nullptr, out, nullptr, M_, V_, D_, stream);
}

// Round 7
// 4686.050 us; speedup vs baseline: 1.1296x; 1.0904x over previous
//
#include <hip/hip_runtime.h>
#include <cmath>

#define V_ 50257
#define D_ 640
#define NL_ 16
#define DF_ 2560
#define R_ 24
#define DG_ 256
#define PLU_ 276
#define PLUP_ 288
#define B_ 4
#define L_ 1024
#define M_ (B_*L_)
#define EPS_ 1e-6f
#define LN_EPS_ 1e-5f

typedef __bf16 bf16x8 __attribute__((ext_vector_type(8)));
typedef float f32x4 __attribute__((ext_vector_type(4)));

__device__ __forceinline__ float gelu_exact(float x) {
    return 0.5f * x * (1.0f + erff(x * 0.70710678118654752f));
}
__device__ __forceinline__ float sigmoid_f(float x) {
    return 1.0f / (1.0f + expf(-x));
}
__device__ __forceinline__ ushort f2b(float f) {
    union { float f; unsigned u; } v; v.f = f;
    unsigned u = v.u;
    return (ushort)((u + 0x7FFFu + ((u >> 16) & 1u)) >> 16);
}
__device__ __forceinline__ float b2f(ushort b) {
    union { unsigned u; float f; } v; v.u = ((unsigned)b) << 16;
    return v.f;
}

#define GLOAD16(gptr, lptr) \
    __builtin_amdgcn_global_load_lds((const __attribute__((address_space(1))) void*)(gptr), \
                                     (__attribute__((address_space(3))) void*)(lptr), 16, 0, 0)

// LEDGER:
// R4: XCD remap regressed (lm_head FETCH 288->830MB). Natural blockIdx order.
// R2->R3: LDS XOR-swizzle: SQ_LDS_BANK_CONFLICT 3.2e7 -> 0. Keep.
// R6: 3-stage counted-vmcnt pipeline FAILED correctness (absmax 0.57, race
//     suspected; m152-class sync-structure edit). REVERTED to the 2-phase
//     {STAGE(next); ds_read+MFMA(cur); vmcnt(0); barrier} that passed R4+R5.
//     Do not re-add deeper pipelining without isolated race screening.

// ---------------------------------------------------------------------------
// 128x128 tile, 4 waves (2x2), each wave 64x64 = 4x4 frags of 16x16x32.
// EPI: 0 = f32 coalesced out via LDS-transposed epilogue (lm_head is
//      write-heavy: strided 1-f32/lane stores measured 1.47x ideal WRITE);
//      1 = gelu->bf16 out; 4 = bf16 out
// ---------------------------------------------------------------------------
#define AS_(b) (shmem + (b) * 4096)
#define BS_(b) (shmem + 8192 + (b) * 4096)
#define STAGE128(b, k0) do { \
    GLOAD16(A + (size_t)(bm + w * 32 + srow) * (size_t)K + ((k0) + scol), AS_(b) + (w * 32) * 32); \
    GLOAD16(A + (size_t)(bm + w * 32 + 16 + srow) * (size_t)K + ((k0) + scol), AS_(b) + (w * 32 + 16) * 32); \
    int rb0_ = bn + w * 32 + srow;      if (rb0_ > N - 1) rb0_ = N - 1; \
    int rb1_ = bn + w * 32 + 16 + srow; if (rb1_ > N - 1) rb1_ = N - 1; \
    GLOAD16(W + (size_t)rb0_ * (size_t)K + ((k0) + scol), BS_(b) + (w * 32) * 32); \
    GLOAD16(W + (size_t)rb1_ * (size_t)K + ((k0) + scol), BS_(b) + (w * 32 + 16) * 32); \
} while (0)

template<int EPI>
__global__ __launch_bounds__(256) void mgemm128_k(
    const ushort* __restrict__ A, const ushort* __restrict__ W,
    const float* __restrict__ bias, float* __restrict__ Cf,
    ushort* __restrict__ Cb, int M, int N, int K)
{
    __shared__ ushort shmem[16384];   // As[2][4096] | Bs[2][4096]
    const int tid = threadIdx.x;
    const int lane = tid & 63;
    const int w = tid >> 6;
    const int wr = w >> 1, wc = w & 1;
    const int lr = lane & 15, lk = lane >> 4;
    const int bm = blockIdx.x * 128, bn = blockIdx.y * 128;
    const int srow = lane >> 2;
    const int scol = (((lane & 3) ^ ((srow >> 1) & 3)) * 8);

    f32x4 acc[4][4] = {};
    const int nt = K >> 5;

    STAGE128(0, 0);
    asm volatile("s_waitcnt vmcnt(0)" ::: "memory");
    __builtin_amdgcn_s_barrier();

    int cur = 0;
    for (int t = 0; t < nt; ++t) {
        if (t + 1 < nt) { STAGE128(cur ^ 1, (t + 1) * 32); }
        bf16x8 af[4], bfr[4];
        #pragma unroll
        for (int m = 0; m < 4; ++m) {
            int rr = wr * 64 + m * 16 + lr;
            af[m] = *reinterpret_cast<const bf16x8*>(&AS_(cur)[rr * 32 + ((lk ^ ((rr >> 1) & 3)) * 8)]);
        }
        #pragma unroll
        for (int n = 0; n < 4; ++n) {
            int rr = wc * 64 + n * 16 + lr;
            bfr[n] = *reinterpret_cast<const bf16x8*>(&BS_(cur)[rr * 32 + ((lk ^ ((rr >> 1) & 3)) * 8)]);
        }
        #pragma unroll
        for (int m = 0; m < 4; ++m)
            #pragma unroll
            for (int n = 0; n < 4; ++n)
                acc[m][n] = __builtin_amdgcn_mfma_f32_16x16x32_bf16(af[m], bfr[n], acc[m][n], 0, 0, 0);
        asm volatile("s_waitcnt vmcnt(0)" ::: "memory");
        __builtin_amdgcn_s_barrier();
        cur ^= 1;
    }

    if (EPI == 0) {
        // Coalesced f32 epilogue: per-wave 16x64 transpose via LDS (reuses
        // staging block; all loads drained by the final vmcnt(0)+barrier).
        // Each store writes 256B contiguous per wave.
        float* lds_f = (float*)shmem;
        const int wbase = w * (16 * 68);
        #pragma unroll
        for (int m = 0; m < 4; ++m) {
            #pragma unroll
            for (int n = 0; n < 4; ++n) {
                float bsv = bias ? bias[bn + wc * 64 + n * 16 + lr] : 0.0f;
                #pragma unroll
                for (int r4 = 0; r4 < 4; ++r4)
                    lds_f[wbase + (lk * 4 + r4) * 68 + n * 16 + lr] = acc[m][n][r4] + bsv;
            }
            __syncthreads();
            #pragma unroll
            for (int r = 0; r < 16; ++r) {
                int row = bm + wr * 64 + m * 16 + r;
                int col = bn + wc * 64 + lane;
                float v = lds_f[wbase + r * 68 + lane];
                if (col < N) Cf[(size_t)row * N + col] = v;
            }
            __syncthreads();
        }
    } else {
        #pragma unroll
        for (int n = 0; n < 4; ++n) {
            int col = bn + wc * 64 + n * 16 + lr;
            if (col >= N) continue;
            float bsv = bias ? bias[col] : 0.0f;
            #pragma unroll
            for (int m = 0; m < 4; ++m) {
                #pragma unroll
                for (int r4 = 0; r4 < 4; ++r4) {
                    int row = bm + wr * 64 + m * 16 + lk * 4 + r4;
                    float o = acc[m][n][r4] + bsv;
                    size_t idx = (size_t)row * N + col;
                    if (EPI == 1) Cb[idx] = f2b(gelu_exact(o));
                    else          Cb[idx] = f2b(o);
                }
            }
        }
    }
}

// ---------------------------------------------------------------------------
// 128x64 tile, 4 waves, wave 64x32 = 4x2 frags. R5 2-phase pipeline.
// EPI==2: alpha=sigmoid(o); Cf(x) += a*h + (1-a)*g. EPI==3: Cf += o.
// ---------------------------------------------------------------------------
#define STAGE12864(b, k0) do { \
    GLOAD16(A + (size_t)(bm + w * 16 + srow) * (size_t)K + ((k0) + scol), &As[b][(w * 16) * 32]); \
    GLOAD16(A + (size_t)(bm + 64 + w * 16 + srow) * (size_t)K + ((k0) + scol), &As[b][(64 + w * 16) * 32]); \
    GLOAD16(W + (size_t)(bn + w * 16 + srow) * (size_t)K + ((k0) + scol), &Bs[b][(w * 16) * 32]); \
} while (0)

template<int EPI>
__global__ __launch_bounds__(256) void mgemm12864_k(
    const ushort* __restrict__ A, const ushort* __restrict__ W,
    const float* __restrict__ bias, float* __restrict__ Cf,
    const float* __restrict__ hbuf, const float* __restrict__ gbuf,
    int M, int N, int K)
{
    __shared__ ushort As[2][128 * 32];
    __shared__ ushort Bs[2][64 * 32];
    const int tid = threadIdx.x;
    const int lane = tid & 63;
    const int w = tid >> 6;
    const int wr = w >> 1, wc = w & 1;
    const int lr = lane & 15, lk = lane >> 4;
    const int bm = blockIdx.x * 128, bn = blockIdx.y * 64;
    const int srow = lane >> 2;
    const int scol = (((lane & 3) ^ ((srow >> 1) & 3)) * 8);

    f32x4 acc[4][2] = {};
    const int nt = K >> 5;

    STAGE12864(0, 0);
    asm volatile("s_waitcnt vmcnt(0)" ::: "memory");
    __builtin_amdgcn_s_barrier();

    int cur = 0;
    for (int t = 0; t < nt; ++t) {
        if (t + 1 < nt) { STAGE12864(cur ^ 1, (t + 1) * 32); }
        bf16x8 af[4], bfr[2];
        #pragma unroll
        for (int m = 0; m < 4; ++m) {
            int rr = wr * 64 + m * 16 + lr;
            af[m] = *reinterpret_cast<const bf16x8*>(&As[cur][rr * 32 + ((lk ^ ((rr >> 1) & 3)) * 8)]);
        }
        #pragma unroll
        for (int n = 0; n < 2; ++n) {
            int rr = wc * 32 + n * 16 + lr;
            bfr[n] = *reinterpret_cast<const bf16x8*>(&Bs[cur][rr * 32 + ((lk ^ ((rr >> 1) & 3)) * 8)]);
        }
        #pragma unroll
        for (int m = 0; m < 4; ++m)
            #pragma unroll
            for (int n = 0; n < 2; ++n)
                acc[m][n] = __builtin_amdgcn_mfma_f32_16x16x32_bf16(af[m], bfr[n], acc[m][n], 0, 0, 0);
        asm volatile("s_waitcnt vmcnt(0)" ::: "memory");
        __builtin_amdgcn_s_barrier();
        cur ^= 1;
    }

    #pragma unroll
    for (int n = 0; n < 2; ++n) {
        int col = bn + wc * 32 + n * 16 + lr;
        float bsv = bias ? bias[col] : 0.0f;
        #pragma unroll
        for (int m = 0; m < 4; ++m) {
            #pragma unroll
            for (int r4 = 0; r4 < 4; ++r4) {
                int row = bm + wr * 64 + m * 16 + lk * 4 + r4;
                float o = acc[m][n][r4] + bsv;
                size_t idx = (size_t)row * N + col;
                if (EPI == 2) {
                    float a = sigmoid_f(o);
                    Cf[idx] = Cf[idx] + a * hbuf[idx] + (1.0f - a) * gbuf[idx];
                } else {
                    Cf[idx] += o;
                }
            }
        }
    }
}

// ---------------------------------------------------------------------------
// Fused LN1 + red projection: one block (128 thr) per row.
// LN -> h (f32) + hgb (bf16, stride 2D) + hrow (LDS); then z[row,0..23]
// via 24x5 partial dot products over the LDS row.
// ---------------------------------------------------------------------------
__global__ __launch_bounds__(128) void lnred_k(
    const float* __restrict__ x, const float* __restrict__ w,
    const float* __restrict__ b, const float* __restrict__ rw,
    const float* __restrict__ rb, float* __restrict__ hout,
    ushort* __restrict__ hgb, float* __restrict__ z)
{
    int row = blockIdx.x;
    int tid = threadIdx.x;
    const float* xr = x + (size_t)row * D_;
    __shared__ float hrow[D_];
    __shared__ float parts[R_][5];
    float v[5];
    float sum = 0.f, sumsq = 0.f;
    #pragma unroll
    for (int t = 0; t < 5; ++t) {
        v[t] = xr[tid + t * 128];
        sum += v[t]; sumsq += v[t] * v[t];
    }
    #pragma unroll
    for (int off = 32; off > 0; off >>= 1) {
        sum += __shfl_down(sum, off);
        sumsq += __shfl_down(sumsq, off);
    }
    __shared__ float s0[2], s1[2];
    if ((tid & 63) == 0) { s0[tid >> 6] = sum; s1[tid >> 6] = sumsq; }
    __syncthreads();
    float m = (s0[0] + s0[1]) * (1.0f / D_);
    float var = (s1[0] + s1[1]) * (1.0f / D_) - m * m;
    float inv = rsqrtf(var + LN_EPS_);
    #pragma unroll
    for (int t = 0; t < 5; ++t) {
        int d = tid + t * 128;
        float o = (v[t] - m) * inv * w[d] + b[d];
        hout[(size_t)row * D_ + d] = o;
        hgb[(size_t)row * (2 * D_) + d] = f2b(o);
        hrow[d] = o;
    }
    __syncthreads();
    if (tid < 120) {
        int c = tid / 5, ch = tid - c * 5;
        const float4* hv = (const float4*)(hrow + ch * 128);
        const float4* wv = (const float4*)(rw + (size_t)c * D_ + ch * 128);
        float p = 0.f;
        #pragma unroll 8
        for (int k = 0; k < 32; ++k) {
            float4 a = hv[k], bb = wv[k];
            p += a.x * bb.x + a.y * bb.y + a.z * bb.z + a.w * bb.w;
        }
        parts[c][ch] = p;
    }
    __syncthreads();
    if (tid < R_) {
        float s = parts[tid][0] + parts[tid][1] + parts[tid][2] + parts[tid][3] + parts[tid][4];
        z[(size_t)row * R_ + tid] = s + rb[tid];
    }
}

// ---------------------------------------------------------------------------
__global__ __launch_bounds__(256) void embed_k(
    const int* __restrict__ ids, const float* __restrict__ tok,
    const float* __restrict__ pos, float* __restrict__ x)
{
    int idx = blockIdx.x * 256 + threadIdx.x;
    if (idx >= M_ * D_) return;
    int row = idx / D_;
    int d = idx - row * D_;
    int l = row & (L_ - 1);
    x[idx] = tok[(size_t)ids[row] * D_ + d] + pos[(size_t)l * D_ + d];
}

__global__ __launch_bounds__(256) void cvt_k(
    const float* __restrict__ src, ushort* __restrict__ dst, int n)
{
    int idx = blockIdx.x * 256 + threadIdx.x;
    if (idx < n) dst[idx] = f2b(src[idx]);
}

// per-layer weight conversion (gp1 padded 276->288, gp2, gate, fc1, fc2)
#define WC_G1  73728
#define WC_G2  (WC_G1 + 163840)
#define WC_GT  (WC_G2 + 819200)
#define WC_F1  (WC_GT + 1638400)
#define WC_F2  (WC_F1 + 1638400)
__device__ __forceinline__ void wconv_body(
    int idx, const float* g1, const float* g2, const float* gt,
    const float* f1, const float* f2, ushort* wb)
{
    if (idx < WC_G1) {
        int row = idx / PLUP_, c = idx - row * PLUP_;
        wb[idx] = (c < PLU_) ? f2b(g1[row * PLU_ + c]) : (ushort)0;
    } else if (idx < WC_G2) {
        wb[idx] = f2b(g2[idx - WC_G1]);
    } else if (idx < WC_GT) {
        wb[idx] = f2b(gt[idx - WC_G2]);
    } else if (idx < WC_F1) {
        wb[idx] = f2b(f1[idx - WC_GT]);
    } else if (idx < WC_F2) {
        wb[idx] = f2b(f2[idx - WC_F1]);
    }
}

__global__ __launch_bounds__(256) void wconv_k(
    const float* __restrict__ g1, const float* __restrict__ g2,
    const float* __restrict__ gt, const float* __restrict__ f1,
    const float* __restrict__ f2, ushort* __restrict__ wb)
{
    int idx = blockIdx.x * 256 + threadIdx.x;
    wconv_body(idx, g1, g2, gt, f1, f2, wb);
}

// all-layer variant: grid (blocks, NL_); one launch instead of 16.
__global__ __launch_bounds__(256) void wconv_all_k(
    const float* __restrict__ g1, const float* __restrict__ g2,
    const float* __restrict__ gt, const float* __restrict__ f1,
    const float* __restrict__ f2, ushort* __restrict__ wb_all)
{
    int l = blockIdx.y;
    int idx = blockIdx.x * 256 + threadIdx.x;
    wconv_body(idx,
               g1 + (size_t)l * DG_ * PLU_, g2 + (size_t)l * D_ * DG_,
               gt + (size_t)l * D_ * 2 * D_, f1 + (size_t)l * DF_ * D_,
               f2 + (size_t)l * D_ * DF_, wb_all + (size_t)l * WC_F2);
}

// ---------------------------------------------------------------------------
__global__ __launch_bounds__(128) void ln_k(
    const float* __restrict__ x, const float* __restrict__ w,
    const float* __restrict__ b, float* __restrict__ outf,
    ushort* __restrict__ outb, int bstride)
{
    int row = blockIdx.x;
    int tid = threadIdx.x;
    const float* xr = x + (size_t)row * D_;
    float v[5];
    float sum = 0.f, sumsq = 0.f;
    #pragma unroll
    for (int t = 0; t < 5; ++t) {
        v[t] = xr[tid + t * 128];
        sum += v[t]; sumsq += v[t] * v[t];
    }
    #pragma unroll
    for (int off = 32; off > 0; off >>= 1) {
        sum += __shfl_down(sum, off);
        sumsq += __shfl_down(sumsq, off);
    }
    __shared__ float s0[2], s1[2];
    if ((tid & 63) == 0) { s0[tid >> 6] = sum; s1[tid >> 6] = sumsq; }
    __syncthreads();
    float m = (s0[0] + s0[1]) * (1.0f / D_);
    float var = (s1[0] + s1[1]) * (1.0f / D_) - m * m;
    float inv = rsqrtf(var + LN_EPS_);
    #pragma unroll
    for (int t = 0; t < 5; ++t) {
        int d = tid + t * 128;
        float o = (v[t] - m) * inv * w[d] + b[d];
        if (outf) outf[(size_t)row * D_ + d] = o;
        if (outb) outb[(size_t)row * bstride + d] = f2b(o);
    }
}

// ---------------------------------------------------------------------------
__global__ __launch_bounds__(128) void plucker7_k(
    const float* __restrict__ z, ushort* __restrict__ pb)
{
    int oi = blockIdx.y;
    int delta = 1 << oi;
    int row = blockIdx.x;
    int l = row & (L_ - 1);
    int tid = threadIdx.x;
    ushort* out = pb + ((size_t)oi * M_ + row) * PLUP_;
    if (l < delta) {
        for (int idx = tid; idx < PLUP_; idx += 128) out[idx] = 0;
        return;
    }
    __shared__ float zc[R_], zp[R_];
    if (tid < R_) {
        zc[tid] = z[(size_t)row * R_ + tid];
        zp[tid] = z[(size_t)(row - delta) * R_ + tid];
    }
    __syncthreads();
    float vals[3];
    float ss = 0.f;
    #pragma unroll
    for (int t = 0; t < 3; ++t) {
        int idx = tid + t * 128;
        float val = 0.f;
        if (idx < PLU_) {
            int i = 0, rem = idx;
            while (rem >= 23 - i) { rem -= 23 - i; ++i; }
            int j = i + 1 + rem;
            val = zp[i] * zc[j] - zp[j] * zc[i];
        }
        vals[t] = val;
        ss += val * val;
    }
    #pragma unroll
    for (int off = 32; off > 0; off >>= 1) ss += __shfl_down(ss, off);
    __shared__ float wsum[2];
    if ((tid & 63) == 0) wsum[tid >> 6] = ss;
    __syncthreads();
    float inv = 1.0f / fmaxf(sqrtf(wsum[0] + wsum[1]), EPS_);
    #pragma unroll
    for (int t = 0; t < 3; ++t) {
        int idx = tid + t * 128;
        if (idx < PLUP_) out[idx] = (idx < PLU_) ? f2b(vals[t] * inv) : (ushort)0;
    }
}

// ---------------------------------------------------------------------------
__global__ __launch_bounds__(256) void greduce_k(
    const ushort* __restrict__ gbigb, float* __restrict__ g,
    ushort* __restrict__ hgb)
{
    int idx = blockIdx.x * 256 + threadIdx.x;
    if (idx >= M_ * D_) return;
    int row = idx / D_;
    int d = idx - row * D_;
    int l = row & (L_ - 1);
    float s = 0.f;
    int c = 0;
    #pragma unroll
    for (int oi = 0; oi < 7; ++oi) {
        if (l >= (1 << oi)) {
            s += b2f(gbigb[(size_t)oi * M_ * D_ + idx]);
            ++c;
        }
    }
    float gv = s / (float)max(c, 1);
    g[idx] = gv;
    hgb[(size_t)row * (2 * D_) + D_ + d] = f2b(gv);
}

// ---------------------------------------------------------------------------
static void mg128(int epi, const ushort* A, const ushort* W, const float* bias,
                  float* Cf, ushort* Cb, int M, int N, int K, hipStream_t s)
{
    dim3 grid(M / 128, (N + 127) / 128), block(256);
    if (epi == 0)      mgemm128_k<0><<<grid, block, 0, s>>>(A, W, bias, Cf, Cb, M, N, K);
    else if (epi == 1) mgemm128_k<1><<<grid, block, 0, s>>>(A, W, bias, Cf, Cb, M, N, K);
    else               mgemm128_k<4><<<grid, block, 0, s>>>(A, W, bias, Cf, Cb, M, N, K);
}

static void mg12864(int epi, const ushort* A, const ushort* W, const float* bias,
                    float* Cf, const float* h, const float* g, int M, int N, int K,
                    hipStream_t s)
{
    dim3 grid(M / 128, N / 64), block(256);
    if (epi == 2) mgemm12864_k<2><<<grid, block, 0, s>>>(A, W, bias, Cf, h, g, M, N, K);
    else          mgemm12864_k<3><<<grid, block, 0, s>>>(A, W, bias, Cf, h, g, M, N, K);
}

extern "C" void kernel_launch(void* const* d_in, const int* in_sizes, int n_in,
                              void* d_out, int out_size, void* d_ws, size_t ws_size,
                              hipStream_t stream)
{
    const int*   ids   = (const int*)d_in[0];
    const float* tok   = (const float*)d_in[1];
    const float* pos   = (const float*)d_in[2];
    const float* ln1w  = (const float*)d_in[3];
    const float* ln1b  = (const float*)d_in[4];
    const float* redw  = (const float*)d_in[5];
    const float* redb  = (const float*)d_in[6];
    const float* gp1w  = (const float*)d_in[7];
    const float* gp1b  = (const float*)d_in[8];
    const float* gp2w  = (const float*)d_in[9];
    const float* gp2b  = (const float*)d_in[10];
    const float* gatew = (const float*)d_in[11];
    const float* gateb = (const float*)d_in[12];
    const float* ln2w  = (const float*)d_in[13];
    const float* ln2b  = (const float*)d_in[14];
    const float* fc1w  = (const float*)d_in[15];
    const float* fc1b  = (const float*)d_in[16];
    const float* fc2w  = (const float*)d_in[17];
    const float* fc2b  = (const float*)d_in[18];
    const float* fnw   = (const float*)d_in[19];
    const float* fnb   = (const float*)d_in[20];
    float* out = (float*)d_out;

    const size_t MD = (size_t)M_ * D_;
    float* ws = (float*)d_ws;
    float* x = ws;                       // MD
    float* h = x + MD;                   // MD
    float* g = h + MD;                   // MD
    float* z = g + MD;                   // M_*R_
    ushort* gbigb = (ushort*)(z + (size_t)M_ * R_);       // 7*MD
    ushort* pb    = gbigb + 7 * MD;                       // 7*M_*288
    ushort* c1b   = pb + (size_t)7 * M_ * PLUP_;          // 7*M_*256
    ushort* hgb   = c1b + (size_t)7 * M_ * DG_;           // M_*1280
    ushort* h2b   = hgb + (size_t)M_ * 2 * D_;            // M_*640
    ushort* ffb   = h2b + MD;                             // M_*2560
    ushort* xnb   = ffb + (size_t)M_ * DF_;               // M_*640
    ushort* tokb  = xnb + MD;                             // V_*640
    ushort* wb    = tokb + (size_t)V_ * D_;               // WC_F2 (or x16)

    const size_t base_bytes = (size_t)((char*)wb - (char*)d_ws);
    const bool all_w = ws_size >= base_bytes + (size_t)NL_ * WC_F2 * 2;

    const int ELT_GRID = (M_ * D_ + 255) / 256;
    const int WC_GRID = (WC_F2 + 255) / 256;

    embed_k<<<ELT_GRID, 256, 0, stream>>>(ids, tok, pos, x);
    cvt_k<<<(V_ * D_ + 255) / 256, 256, 0, stream>>>(tok, tokb, V_ * D_);
    if (all_w)
        wconv_all_k<<<dim3(WC_GRID, NL_), 256, 0, stream>>>(gp1w, gp2w, gatew, fc1w, fc2w, wb);

    for (int l = 0; l < NL_; ++l) {
        const ushort* wbl = all_w ? wb + (size_t)l * WC_F2 : wb;
        if (!all_w)
            wconv_k<<<WC_GRID, 256, 0, stream>>>(
                gp1w + (size_t)l * DG_ * PLU_, gp2w + (size_t)l * D_ * DG_,
                gatew + (size_t)l * D_ * 2 * D_, fc1w + (size_t)l * DF_ * D_,
                fc2w + (size_t)l * D_ * DF_, wb);
        lnred_k<<<M_, 128, 0, stream>>>(x, ln1w + (size_t)l * D_, ln1b + (size_t)l * D_,
                                        redw + (size_t)l * R_ * D_, redb + (size_t)l * R_,
                                        h, hgb, z);
        plucker7_k<<<dim3(M_, 7), 128, 0, stream>>>(z, pb);
        mg128(1, pb, wbl, gp1b + (size_t)l * DG_, nullptr, c1b, 7 * M_, DG_, PLUP_, stream);
        mg128(4, c1b, wbl + WC_G1, gp2b + (size_t)l * D_, nullptr, gbigb, 7 * M_, D_, DG_, stream);
        greduce_k<<<ELT_GRID, 256, 0, stream>>>(gbigb, g, hgb);
        mg12864(2, hgb, wbl + WC_G2, gateb + (size_t)l * D_, x, h, g, M_, D_, 2 * D_, stream);
        ln_k<<<M_, 128, 0, stream>>>(x, ln2w + (size_t)l * D_, ln2b + (size_t)l * D_,
                                     nullptr, h2b, D_);
        mg128(1, h2b, wbl + WC_GT, fc1b + (size_t)l * DF_, nullptr, ffb, M_, DF_, D_, stream);
        mg12864(3, ffb, wbl + WC_F1, fc2b + (size_t)l * D_, x, nullptr, nullptr, M_, D_, DF_, stream);
    }
    ln_k<<<M_, 128, 0, stream>>>(x, fnw, fnb, nullptr, xnb, D_);
    mg128(0, xnb, tokb, nullptr, out, nullptr, M_, V_, D_, stream);
}

// Round 8
// 4191.338 us; speedup vs baseline: 1.2629x; 1.1180x over previous
//
#include <hip/hip_runtime.h>
#include <cmath>

#define V_ 50257
#define D_ 640
#define NL_ 16
#define DF_ 2560
#define R_ 24
#define DG_ 256
#define PLU_ 276
#define PLUP_ 288
#define B_ 4
#define L_ 1024
#define M_ (B_*L_)
#define EPS_ 1e-6f
#define LN_EPS_ 1e-5f

typedef __bf16 bf16x8 __attribute__((ext_vector_type(8)));
typedef float f32x4 __attribute__((ext_vector_type(4)));

__device__ __forceinline__ float gelu_exact(float x) {
    return 0.5f * x * (1.0f + erff(x * 0.70710678118654752f));
}
__device__ __forceinline__ float sigmoid_f(float x) {
    return 1.0f / (1.0f + expf(-x));
}
__device__ __forceinline__ ushort f2b(float f) {
    union { float f; unsigned u; } v; v.f = f;
    unsigned u = v.u;
    return (ushort)((u + 0x7FFFu + ((u >> 16) & 1u)) >> 16);
}
__device__ __forceinline__ float b2f(ushort b) {
    union { unsigned u; float f; } v; v.u = ((unsigned)b) << 16;
    return v.f;
}

#define GLOAD16(gptr, lptr) \
    __builtin_amdgcn_global_load_lds((const __attribute__((address_space(1))) void*)(gptr), \
                                     (__attribute__((address_space(3))) void*)(lptr), 16, 0, 0)

// LEDGER:
// R4: XCD remap regressed (lm_head FETCH 288->830MB). Natural blockIdx order.
// R2->R3: LDS XOR-swizzle: SQ_LDS_BANK_CONFLICT 3.2e7 -> 0. Keep.
// R6: 3-stage counted-vmcnt pipeline FAILED correctness (absmax 0.57; m152-
//     class sync edit). 2-phase {STAGE(next); MFMA(cur); vmcnt(0); barrier}
//     is the verified schedule (R4,R5,R7). No deeper pipelining w/o screening.
// R7: coalesced LDS-transpose f32 epilogue: lm_head 554 -> <480us. Keep.
// R8: gp2 linearity fusion -- sum gelu outputs over deltas FIRST (credsum),
//     then gp2 on M rows instead of 7M (7x FLOP cut); greduce deleted.

// ---------------------------------------------------------------------------
// 128x128 tile, 4 waves (2x2), each wave 64x64 = 4x4 frags of 16x16x32.
// EPI: 0 = f32 coalesced out (LDS transpose); 1 = gelu->bf16; 4 = bf16
// ---------------------------------------------------------------------------
#define AS_(b) (shmem + (b) * 4096)
#define BS_(b) (shmem + 8192 + (b) * 4096)
#define STAGE128(b, k0) do { \
    GLOAD16(A + (size_t)(bm + w * 32 + srow) * (size_t)K + ((k0) + scol), AS_(b) + (w * 32) * 32); \
    GLOAD16(A + (size_t)(bm + w * 32 + 16 + srow) * (size_t)K + ((k0) + scol), AS_(b) + (w * 32 + 16) * 32); \
    int rb0_ = bn + w * 32 + srow;      if (rb0_ > N - 1) rb0_ = N - 1; \
    int rb1_ = bn + w * 32 + 16 + srow; if (rb1_ > N - 1) rb1_ = N - 1; \
    GLOAD16(W + (size_t)rb0_ * (size_t)K + ((k0) + scol), BS_(b) + (w * 32) * 32); \
    GLOAD16(W + (size_t)rb1_ * (size_t)K + ((k0) + scol), BS_(b) + (w * 32 + 16) * 32); \
} while (0)

template<int EPI>
__global__ __launch_bounds__(256) void mgemm128_k(
    const ushort* __restrict__ A, const ushort* __restrict__ W,
    const float* __restrict__ bias, float* __restrict__ Cf,
    ushort* __restrict__ Cb, int M, int N, int K)
{
    __shared__ ushort shmem[16384];   // As[2][4096] | Bs[2][4096]
    const int tid = threadIdx.x;
    const int lane = tid & 63;
    const int w = tid >> 6;
    const int wr = w >> 1, wc = w & 1;
    const int lr = lane & 15, lk = lane >> 4;
    const int bm = blockIdx.x * 128, bn = blockIdx.y * 128;
    const int srow = lane >> 2;
    const int scol = (((lane & 3) ^ ((srow >> 1) & 3)) * 8);

    f32x4 acc[4][4] = {};
    const int nt = K >> 5;

    STAGE128(0, 0);
    asm volatile("s_waitcnt vmcnt(0)" ::: "memory");
    __builtin_amdgcn_s_barrier();

    int cur = 0;
    for (int t = 0; t < nt; ++t) {
        if (t + 1 < nt) { STAGE128(cur ^ 1, (t + 1) * 32); }
        bf16x8 af[4], bfr[4];
        #pragma unroll
        for (int m = 0; m < 4; ++m) {
            int rr = wr * 64 + m * 16 + lr;
            af[m] = *reinterpret_cast<const bf16x8*>(&AS_(cur)[rr * 32 + ((lk ^ ((rr >> 1) & 3)) * 8)]);
        }
        #pragma unroll
        for (int n = 0; n < 4; ++n) {
            int rr = wc * 64 + n * 16 + lr;
            bfr[n] = *reinterpret_cast<const bf16x8*>(&BS_(cur)[rr * 32 + ((lk ^ ((rr >> 1) & 3)) * 8)]);
        }
        #pragma unroll
        for (int m = 0; m < 4; ++m)
            #pragma unroll
            for (int n = 0; n < 4; ++n)
                acc[m][n] = __builtin_amdgcn_mfma_f32_16x16x32_bf16(af[m], bfr[n], acc[m][n], 0, 0, 0);
        asm volatile("s_waitcnt vmcnt(0)" ::: "memory");
        __builtin_amdgcn_s_barrier();
        cur ^= 1;
    }

    if (EPI == 0) {
        float* lds_f = (float*)shmem;
        const int wbase = w * (16 * 68);
        #pragma unroll
        for (int m = 0; m < 4; ++m) {
            #pragma unroll
            for (int n = 0; n < 4; ++n) {
                float bsv = bias ? bias[bn + wc * 64 + n * 16 + lr] : 0.0f;
                #pragma unroll
                for (int r4 = 0; r4 < 4; ++r4)
                    lds_f[wbase + (lk * 4 + r4) * 68 + n * 16 + lr] = acc[m][n][r4] + bsv;
            }
            __syncthreads();
            #pragma unroll
            for (int r = 0; r < 16; ++r) {
                int row = bm + wr * 64 + m * 16 + r;
                int col = bn + wc * 64 + lane;
                float v = lds_f[wbase + r * 68 + lane];
                if (col < N) Cf[(size_t)row * N + col] = v;
            }
            __syncthreads();
        }
    } else {
        #pragma unroll
        for (int n = 0; n < 4; ++n) {
            int col = bn + wc * 64 + n * 16 + lr;
            if (col >= N) continue;
            float bsv = bias ? bias[col] : 0.0f;
            #pragma unroll
            for (int m = 0; m < 4; ++m) {
                #pragma unroll
                for (int r4 = 0; r4 < 4; ++r4) {
                    int row = bm + wr * 64 + m * 16 + lk * 4 + r4;
                    float o = acc[m][n][r4] + bsv;
                    size_t idx = (size_t)row * N + col;
                    if (EPI == 1) Cb[idx] = f2b(gelu_exact(o));
                    else          Cb[idx] = f2b(o);
                }
            }
        }
    }
}

// ---------------------------------------------------------------------------
// 128x64 tile, 4 waves, wave 64x32 = 4x2 frags. 2-phase pipeline.
// EPI==2: alpha=sigmoid(o); Cf(x) += a*h + (1-a)*g.
// EPI==3: Cf += o.
// EPI==5: g-write (gp2 after credsum): l==0 -> 0; Cf=g f32; ub=hgb bf16 at D+col.
// ---------------------------------------------------------------------------
#define STAGE12864(b, k0) do { \
    GLOAD16(A + (size_t)(bm + w * 16 + srow) * (size_t)K + ((k0) + scol), &As[b][(w * 16) * 32]); \
    GLOAD16(A + (size_t)(bm + 64 + w * 16 + srow) * (size_t)K + ((k0) + scol), &As[b][(64 + w * 16) * 32]); \
    GLOAD16(W + (size_t)(bn + w * 16 + srow) * (size_t)K + ((k0) + scol), &Bs[b][(w * 16) * 32]); \
} while (0)

template<int EPI>
__global__ __launch_bounds__(256) void mgemm12864_k(
    const ushort* __restrict__ A, const ushort* __restrict__ W,
    const float* __restrict__ bias, float* __restrict__ Cf,
    const float* __restrict__ hbuf, const float* __restrict__ gbuf,
    ushort* __restrict__ ub, int M, int N, int K)
{
    __shared__ ushort As[2][128 * 32];
    __shared__ ushort Bs[2][64 * 32];
    const int tid = threadIdx.x;
    const int lane = tid & 63;
    const int w = tid >> 6;
    const int wr = w >> 1, wc = w & 1;
    const int lr = lane & 15, lk = lane >> 4;
    const int bm = blockIdx.x * 128, bn = blockIdx.y * 64;
    const int srow = lane >> 2;
    const int scol = (((lane & 3) ^ ((srow >> 1) & 3)) * 8);

    f32x4 acc[4][2] = {};
    const int nt = K >> 5;

    STAGE12864(0, 0);
    asm volatile("s_waitcnt vmcnt(0)" ::: "memory");
    __builtin_amdgcn_s_barrier();

    int cur = 0;
    for (int t = 0; t < nt; ++t) {
        if (t + 1 < nt) { STAGE12864(cur ^ 1, (t + 1) * 32); }
        bf16x8 af[4], bfr[2];
        #pragma unroll
        for (int m = 0; m < 4; ++m) {
            int rr = wr * 64 + m * 16 + lr;
            af[m] = *reinterpret_cast<const bf16x8*>(&As[cur][rr * 32 + ((lk ^ ((rr >> 1) & 3)) * 8)]);
        }
        #pragma unroll
        for (int n = 0; n < 2; ++n) {
            int rr = wc * 32 + n * 16 + lr;
            bfr[n] = *reinterpret_cast<const bf16x8*>(&Bs[cur][rr * 32 + ((lk ^ ((rr >> 1) & 3)) * 8)]);
        }
        #pragma unroll
        for (int m = 0; m < 4; ++m)
            #pragma unroll
            for (int n = 0; n < 2; ++n)
                acc[m][n] = __builtin_amdgcn_mfma_f32_16x16x32_bf16(af[m], bfr[n], acc[m][n], 0, 0, 0);
        asm volatile("s_waitcnt vmcnt(0)" ::: "memory");
        __builtin_amdgcn_s_barrier();
        cur ^= 1;
    }

    #pragma unroll
    for (int n = 0; n < 2; ++n) {
        int col = bn + wc * 32 + n * 16 + lr;
        float bsv = bias ? bias[col] : 0.0f;
        #pragma unroll
        for (int m = 0; m < 4; ++m) {
            #pragma unroll
            for (int r4 = 0; r4 < 4; ++r4) {
                int row = bm + wr * 64 + m * 16 + lk * 4 + r4;
                float o = acc[m][n][r4] + bsv;
                size_t idx = (size_t)row * N + col;
                if (EPI == 2) {
                    float a = sigmoid_f(o);
                    Cf[idx] = Cf[idx] + a * hbuf[idx] + (1.0f - a) * gbuf[idx];
                } else if (EPI == 3) {
                    Cf[idx] += o;
                } else if (EPI == 5) {
                    if ((row & (L_ - 1)) == 0) o = 0.0f;   // count==0 rows: g = 0
                    Cf[idx] = o;
                    ub[(size_t)row * (2 * D_) + D_ + col] = f2b(o);
                }
            }
        }
    }
}

// ---------------------------------------------------------------------------
// credsum: cravg[row, c] = (sum over valid deltas of c1[d,row,c]) / count.
// bf16 in/out, f32 accumulate, ushort4-vectorized.
// ---------------------------------------------------------------------------
__global__ __launch_bounds__(256) void credsum_k(
    const ushort* __restrict__ c1b, ushort* __restrict__ crb)
{
    int idx4 = blockIdx.x * 256 + threadIdx.x;
    if (idx4 >= M_ * DG_ / 4) return;
    int idx = idx4 * 4;
    int row = idx / DG_;
    int l = row & (L_ - 1);
    float s0 = 0.f, s1 = 0.f, s2 = 0.f, s3 = 0.f;
    int c = 0;
    #pragma unroll
    for (int oi = 0; oi < 7; ++oi) {
        if (l >= (1 << oi)) {
            ushort4 v = *reinterpret_cast<const ushort4*>(c1b + (size_t)oi * M_ * DG_ + idx);
            s0 += b2f(v.x); s1 += b2f(v.y); s2 += b2f(v.z); s3 += b2f(v.w);
            ++c;
        }
    }
    float inv = 1.0f / (float)max(c, 1);
    ushort4 o;
    o.x = f2b(s0 * inv); o.y = f2b(s1 * inv); o.z = f2b(s2 * inv); o.w = f2b(s3 * inv);
    *reinterpret_cast<ushort4*>(crb + idx) = o;
}

// ---------------------------------------------------------------------------
// Fused LN1 + red projection: one block (128 thr) per row.
// ---------------------------------------------------------------------------
__global__ __launch_bounds__(128) void lnred_k(
    const float* __restrict__ x, const float* __restrict__ w,
    const float* __restrict__ b, const float* __restrict__ rw,
    const float* __restrict__ rb, float* __restrict__ hout,
    ushort* __restrict__ hgb, float* __restrict__ z)
{
    int row = blockIdx.x;
    int tid = threadIdx.x;
    const float* xr = x + (size_t)row * D_;
    __shared__ float hrow[D_];
    __shared__ float parts[R_][5];
    float v[5];
    float sum = 0.f, sumsq = 0.f;
    #pragma unroll
    for (int t = 0; t < 5; ++t) {
        v[t] = xr[tid + t * 128];
        sum += v[t]; sumsq += v[t] * v[t];
    }
    #pragma unroll
    for (int off = 32; off > 0; off >>= 1) {
        sum += __shfl_down(sum, off);
        sumsq += __shfl_down(sumsq, off);
    }
    __shared__ float s0[2], s1[2];
    if ((tid & 63) == 0) { s0[tid >> 6] = sum; s1[tid >> 6] = sumsq; }
    __syncthreads();
    float m = (s0[0] + s0[1]) * (1.0f / D_);
    float var = (s1[0] + s1[1]) * (1.0f / D_) - m * m;
    float inv = rsqrtf(var + LN_EPS_);
    #pragma unroll
    for (int t = 0; t < 5; ++t) {
        int d = tid + t * 128;
        float o = (v[t] - m) * inv * w[d] + b[d];
        hout[(size_t)row * D_ + d] = o;
        hgb[(size_t)row * (2 * D_) + d] = f2b(o);
        hrow[d] = o;
    }
    __syncthreads();
    if (tid < 120) {
        int c = tid / 5, ch = tid - c * 5;
        const float4* hv = (const float4*)(hrow + ch * 128);
        const float4* wv = (const float4*)(rw + (size_t)c * D_ + ch * 128);
        float p = 0.f;
        #pragma unroll 8
        for (int k = 0; k < 32; ++k) {
            float4 a = hv[k], bb = wv[k];
            p += a.x * bb.x + a.y * bb.y + a.z * bb.z + a.w * bb.w;
        }
        parts[c][ch] = p;
    }
    __syncthreads();
    if (tid < R_) {
        float s = parts[tid][0] + parts[tid][1] + parts[tid][2] + parts[tid][3] + parts[tid][4];
        z[(size_t)row * R_ + tid] = s + rb[tid];
    }
}

// ---------------------------------------------------------------------------
__global__ __launch_bounds__(256) void embed_k(
    const int* __restrict__ ids, const float* __restrict__ tok,
    const float* __restrict__ pos, float* __restrict__ x)
{
    int idx = blockIdx.x * 256 + threadIdx.x;
    if (idx >= M_ * D_) return;
    int row = idx / D_;
    int d = idx - row * D_;
    int l = row & (L_ - 1);
    x[idx] = tok[(size_t)ids[row] * D_ + d] + pos[(size_t)l * D_ + d];
}

__global__ __launch_bounds__(256) void cvt_k(
    const float* __restrict__ src, ushort* __restrict__ dst, int n)
{
    int idx = blockIdx.x * 256 + threadIdx.x;
    if (idx < n) dst[idx] = f2b(src[idx]);
}

// per-layer weight conversion (gp1 padded 276->288, gp2, gate, fc1, fc2)
#define WC_G1  73728
#define WC_G2  (WC_G1 + 163840)
#define WC_GT  (WC_G2 + 819200)
#define WC_F1  (WC_GT + 1638400)
#define WC_F2  (WC_F1 + 1638400)
__device__ __forceinline__ void wconv_body(
    int idx, const float* g1, const float* g2, const float* gt,
    const float* f1, const float* f2, ushort* wb)
{
    if (idx < WC_G1) {
        int row = idx / PLUP_, c = idx - row * PLUP_;
        wb[idx] = (c < PLU_) ? f2b(g1[row * PLU_ + c]) : (ushort)0;
    } else if (idx < WC_G2) {
        wb[idx] = f2b(g2[idx - WC_G1]);
    } else if (idx < WC_GT) {
        wb[idx] = f2b(gt[idx - WC_G2]);
    } else if (idx < WC_F1) {
        wb[idx] = f2b(f1[idx - WC_GT]);
    } else if (idx < WC_F2) {
        wb[idx] = f2b(f2[idx - WC_F1]);
    }
}

__global__ __launch_bounds__(256) void wconv_k(
    const float* __restrict__ g1, const float* __restrict__ g2,
    const float* __restrict__ gt, const float* __restrict__ f1,
    const float* __restrict__ f2, ushort* __restrict__ wb)
{
    int idx = blockIdx.x * 256 + threadIdx.x;
    wconv_body(idx, g1, g2, gt, f1, f2, wb);
}

__global__ __launch_bounds__(256) void wconv_all_k(
    const float* __restrict__ g1, const float* __restrict__ g2,
    const float* __restrict__ gt, const float* __restrict__ f1,
    const float* __restrict__ f2, ushort* __restrict__ wb_all)
{
    int l = blockIdx.y;
    int idx = blockIdx.x * 256 + threadIdx.x;
    wconv_body(idx,
               g1 + (size_t)l * DG_ * PLU_, g2 + (size_t)l * D_ * DG_,
               gt + (size_t)l * D_ * 2 * D_, f1 + (size_t)l * DF_ * D_,
               f2 + (size_t)l * D_ * DF_, wb_all + (size_t)l * WC_F2);
}

// ---------------------------------------------------------------------------
__global__ __launch_bounds__(128) void ln_k(
    const float* __restrict__ x, const float* __restrict__ w,
    const float* __restrict__ b, float* __restrict__ outf,
    ushort* __restrict__ outb, int bstride)
{
    int row = blockIdx.x;
    int tid = threadIdx.x;
    const float* xr = x + (size_t)row * D_;
    float v[5];
    float sum = 0.f, sumsq = 0.f;
    #pragma unroll
    for (int t = 0; t < 5; ++t) {
        v[t] = xr[tid + t * 128];
        sum += v[t]; sumsq += v[t] * v[t];
    }
    #pragma unroll
    for (int off = 32; off > 0; off >>= 1) {
        sum += __shfl_down(sum, off);
        sumsq += __shfl_down(sumsq, off);
    }
    __shared__ float s0[2], s1[2];
    if ((tid & 63) == 0) { s0[tid >> 6] = sum; s1[tid >> 6] = sumsq; }
    __syncthreads();
    float m = (s0[0] + s0[1]) * (1.0f / D_);
    float var = (s1[0] + s1[1]) * (1.0f / D_) - m * m;
    float inv = rsqrtf(var + LN_EPS_);
    #pragma unroll
    for (int t = 0; t < 5; ++t) {
        int d = tid + t * 128;
        float o = (v[t] - m) * inv * w[d] + b[d];
        if (outf) outf[(size_t)row * D_ + d] = o;
        if (outb) outb[(size_t)row * bstride + d] = f2b(o);
    }
}

// ---------------------------------------------------------------------------
__global__ __launch_bounds__(128) void plucker7_k(
    const float* __restrict__ z, ushort* __restrict__ pb)
{
    int oi = blockIdx.y;
    int delta = 1 << oi;
    int row = blockIdx.x;
    int l = row & (L_ - 1);
    int tid = threadIdx.x;
    ushort* out = pb + ((size_t)oi * M_ + row) * PLUP_;
    if (l < delta) {
        for (int idx = tid; idx < PLUP_; idx += 128) out[idx] = 0;
        return;
    }
    __shared__ float zc[R_], zp[R_];
    if (tid < R_) {
        zc[tid] = z[(size_t)row * R_ + tid];
        zp[tid] = z[(size_t)(row - delta) * R_ + tid];
    }
    __syncthreads();
    float vals[3];
    float ss = 0.f;
    #pragma unroll
    for (int t = 0; t < 3; ++t) {
        int idx = tid + t * 128;
        float val = 0.f;
        if (idx < PLU_) {
            int i = 0, rem = idx;
            while (rem >= 23 - i) { rem -= 23 - i; ++i; }
            int j = i + 1 + rem;
            val = zp[i] * zc[j] - zp[j] * zc[i];
        }
        vals[t] = val;
        ss += val * val;
    }
    #pragma unroll
    for (int off = 32; off > 0; off >>= 1) ss += __shfl_down(ss, off);
    __shared__ float wsum[2];
    if ((tid & 63) == 0) wsum[tid >> 6] = ss;
    __syncthreads();
    float inv = 1.0f / fmaxf(sqrtf(wsum[0] + wsum[1]), EPS_);
    #pragma unroll
    for (int t = 0; t < 3; ++t) {
        int idx = tid + t * 128;
        if (idx < PLUP_) out[idx] = (idx < PLU_) ? f2b(vals[t] * inv) : (ushort)0;
    }
}

// ---------------------------------------------------------------------------
static void mg128(int epi, const ushort* A, const ushort* W, const float* bias,
                  float* Cf, ushort* Cb, int M, int N, int K, hipStream_t s)
{
    dim3 grid(M / 128, (N + 127) / 128), block(256);
    if (epi == 0)      mgemm128_k<0><<<grid, block, 0, s>>>(A, W, bias, Cf, Cb, M, N, K);
    else if (epi == 1) mgemm128_k<1><<<grid, block, 0, s>>>(A, W, bias, Cf, Cb, M, N, K);
    else               mgemm128_k<4><<<grid, block, 0, s>>>(A, W, bias, Cf, Cb, M, N, K);
}

static void mg12864(int epi, const ushort* A, const ushort* W, const float* bias,
                    float* Cf, const float* h, const float* g, ushort* ub,
                    int M, int N, int K, hipStream_t s)
{
    dim3 grid(M / 128, N / 64), block(256);
    if (epi == 2)      mgemm12864_k<2><<<grid, block, 0, s>>>(A, W, bias, Cf, h, g, ub, M, N, K);
    else if (epi == 3) mgemm12864_k<3><<<grid, block, 0, s>>>(A, W, bias, Cf, h, g, ub, M, N, K);
    else               mgemm12864_k<5><<<grid, block, 0, s>>>(A, W, bias, Cf, h, g, ub, M, N, K);
}

extern "C" void kernel_launch(void* const* d_in, const int* in_sizes, int n_in,
                              void* d_out, int out_size, void* d_ws, size_t ws_size,
                              hipStream_t stream)
{
    const int*   ids   = (const int*)d_in[0];
    const float* tok   = (const float*)d_in[1];
    const float* pos   = (const float*)d_in[2];
    const float* ln1w  = (const float*)d_in[3];
    const float* ln1b  = (const float*)d_in[4];
    const float* redw  = (const float*)d_in[5];
    const float* redb  = (const float*)d_in[6];
    const float* gp1w  = (const float*)d_in[7];
    const float* gp1b  = (const float*)d_in[8];
    const float* gp2w  = (const float*)d_in[9];
    const float* gp2b  = (const float*)d_in[10];
    const float* gatew = (const float*)d_in[11];
    const float* gateb = (const float*)d_in[12];
    const float* ln2w  = (const float*)d_in[13];
    const float* ln2b  = (const float*)d_in[14];
    const float* fc1w  = (const float*)d_in[15];
    const float* fc1b  = (const float*)d_in[16];
    const float* fc2w  = (const float*)d_in[17];
    const float* fc2b  = (const float*)d_in[18];
    const float* fnw   = (const float*)d_in[19];
    const float* fnb   = (const float*)d_in[20];
    float* out = (float*)d_out;

    const size_t MD = (size_t)M_ * D_;
    float* ws = (float*)d_ws;
    float* x = ws;                       // MD
    float* h = x + MD;                   // MD
    float* g = h + MD;                   // MD
    float* z = g + MD;                   // M_*R_
    ushort* pb    = (ushort*)(z + (size_t)M_ * R_);       // 7*M_*288
    ushort* c1b   = pb + (size_t)7 * M_ * PLUP_;          // 7*M_*256
    ushort* crb   = c1b + (size_t)7 * M_ * DG_;           // M_*256
    ushort* hgb   = crb + (size_t)M_ * DG_;               // M_*1280
    ushort* h2b   = hgb + (size_t)M_ * 2 * D_;            // M_*640
    ushort* ffb   = h2b + MD;                             // M_*2560
    ushort* xnb   = ffb + (size_t)M_ * DF_;               // M_*640
    ushort* tokb  = xnb + MD;                             // V_*640
    ushort* wb    = tokb + (size_t)V_ * D_;               // WC_F2 (or x16)

    const size_t base_bytes = (size_t)((char*)wb - (char*)d_ws);
    const bool all_w = ws_size >= base_bytes + (size_t)NL_ * WC_F2 * 2;

    const int ELT_GRID = (M_ * D_ + 255) / 256;
    const int WC_GRID = (WC_F2 + 255) / 256;

    embed_k<<<ELT_GRID, 256, 0, stream>>>(ids, tok, pos, x);
    cvt_k<<<(V_ * D_ + 255) / 256, 256, 0, stream>>>(tok, tokb, V_ * D_);
    if (all_w)
        wconv_all_k<<<dim3(WC_GRID, NL_), 256, 0, stream>>>(gp1w, gp2w, gatew, fc1w, fc2w, wb);

    for (int l = 0; l < NL_; ++l) {
        const ushort* wbl = all_w ? wb + (size_t)l * WC_F2 : wb;
        if (!all_w)
            wconv_k<<<WC_GRID, 256, 0, stream>>>(
                gp1w + (size_t)l * DG_ * PLU_, gp2w + (size_t)l * D_ * DG_,
                gatew + (size_t)l * D_ * 2 * D_, fc1w + (size_t)l * DF_ * D_,
                fc2w + (size_t)l * D_ * DF_, wb);
        lnred_k<<<M_, 128, 0, stream>>>(x, ln1w + (size_t)l * D_, ln1b + (size_t)l * D_,
                                        redw + (size_t)l * R_ * D_, redb + (size_t)l * R_,
                                        h, hgb, z);
        plucker7_k<<<dim3(M_, 7), 128, 0, stream>>>(z, pb);
        mg128(1, pb, wbl, gp1b + (size_t)l * DG_, nullptr, c1b, 7 * M_, DG_, PLUP_, stream);
        credsum_k<<<(M_ * DG_ / 4 + 255) / 256, 256, 0, stream>>>(c1b, crb);
        // gp2 on M rows (linearity fusion): g = cravg . W2^T + b2; l==0 -> 0
        mg12864(5, crb, wbl + WC_G1, gp2b + (size_t)l * D_, g, nullptr, nullptr, hgb,
                M_, D_, DG_, stream);
        mg12864(2, hgb, wbl + WC_G2, gateb + (size_t)l * D_, x, h, g, nullptr,
                M_, D_, 2 * D_, stream);
        ln_k<<<M_, 128, 0, stream>>>(x, ln2w + (size_t)l * D_, ln2b + (size_t)l * D_,
                                     nullptr, h2b, D_);
        mg128(1, h2b, wbl + WC_GT, fc1b + (size_t)l * DF_, nullptr, ffb, M_, DF_, D_, stream);
        mg12864(3, ffb, wbl + WC_F1, fc2b + (size_t)l * D_, x, nullptr, nullptr, nullptr,
                M_, D_, DF_, stream);
    }
    ln_k<<<M_, 128, 0, stream>>>(x, fnw, fnb, nullptr, xnb, D_);
    mg128(0, xnb, tokb, nullptr, out, nullptr, M_, V_, D_, stream);
}

// Round 10
// 4078.697 us; speedup vs baseline: 1.2978x; 1.0276x over previous
//
#include <hip/hip_runtime.h>
#include <cmath>

#define V_ 50257
#define D_ 640
#define NL_ 16
#define DF_ 2560
#define R_ 24
#define DG_ 256
#define PLU_ 276
#define PLUP_ 288
#define B_ 4
#define L_ 1024
#define M_ (B_*L_)
#define EPS_ 1e-6f
#define LN_EPS_ 1e-5f

typedef __bf16 bf16x8 __attribute__((ext_vector_type(8)));
typedef float f32x4 __attribute__((ext_vector_type(4)));

__device__ __forceinline__ float gelu_exact(float x) {
    return 0.5f * x * (1.0f + erff(x * 0.70710678118654752f));
}
__device__ __forceinline__ float sigmoid_f(float x) {
    return 1.0f / (1.0f + expf(-x));
}
__device__ __forceinline__ ushort f2b(float f) {
    union { float f; unsigned u; } v; v.f = f;
    unsigned u = v.u;
    return (ushort)((u + 0x7FFFu + ((u >> 16) & 1u)) >> 16);
}
__device__ __forceinline__ float b2f(ushort b) {
    union { unsigned u; float f; } v; v.u = ((unsigned)b) << 16;
    return v.f;
}

#define GLOAD16(gptr, lptr) \
    __builtin_amdgcn_global_load_lds((const __attribute__((address_space(1))) void*)(gptr), \
                                     (__attribute__((address_space(3))) void*)(lptr), 16, 0, 0)

// LEDGER:
// R4: XCD remap regressed (lm_head FETCH 288->830MB). Natural blockIdx order.
// R2->R3: LDS XOR-swizzle: SQ_LDS_BANK_CONFLICT 3.2e7 -> 0. Keep.
// R6+R9: 3-stage counted-vmcnt pipeline FAILED correctness TWICE (absmax
//     0.57 / 0.65). R9's trailing s_barrier did NOT fix it: raw s_barrier
//     does not wait lgkmcnt, so a wave can cross with ds_reads issued-but-
//     unserviced and the next iteration's DMA overwrites the lines (rule
//     #18 class). FORBIDDEN without lgkmcnt(0)+sched_barrier(0) screening.
//     The verified schedule is 2-phase: {STAGE(next); ds_read+MFMA(cur);
//     vmcnt(0); s_barrier}  (passed R4,R5,R7,R8).
// R7: coalesced LDS-transpose f32 epilogue: lm_head 554 -> <480us. Keep.
// R8: gp2 linearity fusion (credsum before gp2, 7x FLOP cut): 4686->4191.
// R10: gate epilogue reads h/g from bf16 hgb; f32 h/g buffers deleted
//     (-672MB traffic). Sequential kernel ordering -> race-free.

// ---------------------------------------------------------------------------
// 128x128 tile, 4 waves (2x2), each wave 64x64 = 4x4 frags of 16x16x32.
// 2-phase double-buffered pipeline (verified).
// EPI: 0 = f32 coalesced out (LDS transpose); 1 = gelu->bf16; 4 = bf16
// ---------------------------------------------------------------------------
#define AS_(b) (shmem + (b) * 4096)
#define BS_(b) (shmem + 8192 + (b) * 4096)
#define STAGE128(b, k0) do { \
    GLOAD16(A + (size_t)(bm + w * 32 + srow) * (size_t)K + ((k0) + scol), AS_(b) + (w * 32) * 32); \
    GLOAD16(A + (size_t)(bm + w * 32 + 16 + srow) * (size_t)K + ((k0) + scol), AS_(b) + (w * 32 + 16) * 32); \
    int rb0_ = bn + w * 32 + srow;      if (rb0_ > N - 1) rb0_ = N - 1; \
    int rb1_ = bn + w * 32 + 16 + srow; if (rb1_ > N - 1) rb1_ = N - 1; \
    GLOAD16(W + (size_t)rb0_ * (size_t)K + ((k0) + scol), BS_(b) + (w * 32) * 32); \
    GLOAD16(W + (size_t)rb1_ * (size_t)K + ((k0) + scol), BS_(b) + (w * 32 + 16) * 32); \
} while (0)

template<int EPI>
__global__ __launch_bounds__(256) void mgemm128_k(
    const ushort* __restrict__ A, const ushort* __restrict__ W,
    const float* __restrict__ bias, float* __restrict__ Cf,
    ushort* __restrict__ Cb, int M, int N, int K)
{
    __shared__ ushort shmem[16384];   // As[2][4096] | Bs[2][4096]
    const int tid = threadIdx.x;
    const int lane = tid & 63;
    const int w = tid >> 6;
    const int wr = w >> 1, wc = w & 1;
    const int lr = lane & 15, lk = lane >> 4;
    const int bm = blockIdx.x * 128, bn = blockIdx.y * 128;
    const int srow = lane >> 2;
    const int scol = (((lane & 3) ^ ((srow >> 1) & 3)) * 8);

    f32x4 acc[4][4] = {};
    const int nt = K >> 5;

    STAGE128(0, 0);
    asm volatile("s_waitcnt vmcnt(0)" ::: "memory");
    __builtin_amdgcn_s_barrier();

    int cur = 0;
    for (int t = 0; t < nt; ++t) {
        if (t + 1 < nt) { STAGE128(cur ^ 1, (t + 1) * 32); }
        bf16x8 af[4], bfr[4];
        #pragma unroll
        for (int m = 0; m < 4; ++m) {
            int rr = wr * 64 + m * 16 + lr;
            af[m] = *reinterpret_cast<const bf16x8*>(&AS_(cur)[rr * 32 + ((lk ^ ((rr >> 1) & 3)) * 8)]);
        }
        #pragma unroll
        for (int n = 0; n < 4; ++n) {
            int rr = wc * 64 + n * 16 + lr;
            bfr[n] = *reinterpret_cast<const bf16x8*>(&BS_(cur)[rr * 32 + ((lk ^ ((rr >> 1) & 3)) * 8)]);
        }
        #pragma unroll
        for (int m = 0; m < 4; ++m)
            #pragma unroll
            for (int n = 0; n < 4; ++n)
                acc[m][n] = __builtin_amdgcn_mfma_f32_16x16x32_bf16(af[m], bfr[n], acc[m][n], 0, 0, 0);
        asm volatile("s_waitcnt vmcnt(0)" ::: "memory");
        __builtin_amdgcn_s_barrier();
        cur ^= 1;
    }

    if (EPI == 0) {
        float* lds_f = (float*)shmem;
        const int wbase = w * (16 * 68);
        #pragma unroll
        for (int m = 0; m < 4; ++m) {
            #pragma unroll
            for (int n = 0; n < 4; ++n) {
                float bsv = bias ? bias[bn + wc * 64 + n * 16 + lr] : 0.0f;
                #pragma unroll
                for (int r4 = 0; r4 < 4; ++r4)
                    lds_f[wbase + (lk * 4 + r4) * 68 + n * 16 + lr] = acc[m][n][r4] + bsv;
            }
            __syncthreads();
            #pragma unroll
            for (int r = 0; r < 16; ++r) {
                int row = bm + wr * 64 + m * 16 + r;
                int col = bn + wc * 64 + lane;
                float v = lds_f[wbase + r * 68 + lane];
                if (col < N) Cf[(size_t)row * N + col] = v;
            }
            __syncthreads();
        }
    } else {
        #pragma unroll
        for (int n = 0; n < 4; ++n) {
            int col = bn + wc * 64 + n * 16 + lr;
            if (col >= N) continue;
            float bsv = bias ? bias[col] : 0.0f;
            #pragma unroll
            for (int m = 0; m < 4; ++m) {
                #pragma unroll
                for (int r4 = 0; r4 < 4; ++r4) {
                    int row = bm + wr * 64 + m * 16 + lk * 4 + r4;
                    float o = acc[m][n][r4] + bsv;
                    size_t idx = (size_t)row * N + col;
                    if (EPI == 1) Cb[idx] = f2b(gelu_exact(o));
                    else          Cb[idx] = f2b(o);
                }
            }
        }
    }
}

// ---------------------------------------------------------------------------
// 128x64 tile, 4 waves, wave 64x32 = 4x2 frags. Verified 2-phase pipeline.
// EPI==2: alpha=sigmoid(o); x += a*h + (1-a)*g with h,g read from bf16 hg
//         (stride 2D: h at col, g at D+col).
// EPI==3: Cf += o.
// EPI==5: g-write after credsum: l==0 -> 0; bf16 into hg at D+col.
// ---------------------------------------------------------------------------
#define STAGE12864(b, k0) do { \
    GLOAD16(A + (size_t)(bm + w * 16 + srow) * (size_t)K + ((k0) + scol), &As[b][(w * 16) * 32]); \
    GLOAD16(A + (size_t)(bm + 64 + w * 16 + srow) * (size_t)K + ((k0) + scol), &As[b][(64 + w * 16) * 32]); \
    GLOAD16(W + (size_t)(bn + w * 16 + srow) * (size_t)K + ((k0) + scol), &Bs[b][(w * 16) * 32]); \
} while (0)

template<int EPI>
__global__ __launch_bounds__(256) void mgemm12864_k(
    const ushort* __restrict__ A, const ushort* __restrict__ W,
    const float* __restrict__ bias, float* __restrict__ Cf,
    const ushort* __restrict__ hg, ushort* __restrict__ ub,
    int M, int N, int K)
{
    __shared__ ushort As[2][128 * 32];
    __shared__ ushort Bs[2][64 * 32];
    const int tid = threadIdx.x;
    const int lane = tid & 63;
    const int w = tid >> 6;
    const int wr = w >> 1, wc = w & 1;
    const int lr = lane & 15, lk = lane >> 4;
    const int bm = blockIdx.x * 128, bn = blockIdx.y * 64;
    const int srow = lane >> 2;
    const int scol = (((lane & 3) ^ ((srow >> 1) & 3)) * 8);

    f32x4 acc[4][2] = {};
    const int nt = K >> 5;

    STAGE12864(0, 0);
    asm volatile("s_waitcnt vmcnt(0)" ::: "memory");
    __builtin_amdgcn_s_barrier();

    int cur = 0;
    for (int t = 0; t < nt; ++t) {
        if (t + 1 < nt) { STAGE12864(cur ^ 1, (t + 1) * 32); }
        bf16x8 af[4], bfr[2];
        #pragma unroll
        for (int m = 0; m < 4; ++m) {
            int rr = wr * 64 + m * 16 + lr;
            af[m] = *reinterpret_cast<const bf16x8*>(&As[cur][rr * 32 + ((lk ^ ((rr >> 1) & 3)) * 8)]);
        }
        #pragma unroll
        for (int n = 0; n < 2; ++n) {
            int rr = wc * 32 + n * 16 + lr;
            bfr[n] = *reinterpret_cast<const bf16x8*>(&Bs[cur][rr * 32 + ((lk ^ ((rr >> 1) & 3)) * 8)]);
        }
        #pragma unroll
        for (int m = 0; m < 4; ++m)
            #pragma unroll
            for (int n = 0; n < 2; ++n)
                acc[m][n] = __builtin_amdgcn_mfma_f32_16x16x32_bf16(af[m], bfr[n], acc[m][n], 0, 0, 0);
        asm volatile("s_waitcnt vmcnt(0)" ::: "memory");
        __builtin_amdgcn_s_barrier();
        cur ^= 1;
    }

    #pragma unroll
    for (int n = 0; n < 2; ++n) {
        int col = bn + wc * 32 + n * 16 + lr;
        float bsv = bias ? bias[col] : 0.0f;
        #pragma unroll
        for (int m = 0; m < 4; ++m) {
            #pragma unroll
            for (int r4 = 0; r4 < 4; ++r4) {
                int row = bm + wr * 64 + m * 16 + lk * 4 + r4;
                float o = acc[m][n][r4] + bsv;
                size_t idx = (size_t)row * N + col;
                if (EPI == 2) {
                    float a = sigmoid_f(o);
                    float hv = b2f(hg[(size_t)row * (2 * D_) + col]);
                    float gv = b2f(hg[(size_t)row * (2 * D_) + D_ + col]);
                    Cf[idx] = Cf[idx] + a * hv + (1.0f - a) * gv;
                } else if (EPI == 3) {
                    Cf[idx] += o;
                } else if (EPI == 5) {
                    if ((row & (L_ - 1)) == 0) o = 0.0f;   // count==0 rows: g = 0
                    ub[(size_t)row * (2 * D_) + D_ + col] = f2b(o);
                }
            }
        }
    }
}

// ---------------------------------------------------------------------------
// credsum: cravg[row, c] = (sum over valid deltas of c1[d,row,c]) / count.
// ---------------------------------------------------------------------------
__global__ __launch_bounds__(256) void credsum_k(
    const ushort* __restrict__ c1b, ushort* __restrict__ crb)
{
    int idx4 = blockIdx.x * 256 + threadIdx.x;
    if (idx4 >= M_ * DG_ / 4) return;
    int idx = idx4 * 4;
    int row = idx / DG_;
    int l = row & (L_ - 1);
    float s0 = 0.f, s1 = 0.f, s2 = 0.f, s3 = 0.f;
    int c = 0;
    #pragma unroll
    for (int oi = 0; oi < 7; ++oi) {
        if (l >= (1 << oi)) {
            ushort4 v = *reinterpret_cast<const ushort4*>(c1b + (size_t)oi * M_ * DG_ + idx);
            s0 += b2f(v.x); s1 += b2f(v.y); s2 += b2f(v.z); s3 += b2f(v.w);
            ++c;
        }
    }
    float inv = 1.0f / (float)max(c, 1);
    ushort4 o;
    o.x = f2b(s0 * inv); o.y = f2b(s1 * inv); o.z = f2b(s2 * inv); o.w = f2b(s3 * inv);
    *reinterpret_cast<ushort4*>(crb + idx) = o;
}

// ---------------------------------------------------------------------------
// Fused LN1 + red projection: one block (128 thr) per row.
// ---------------------------------------------------------------------------
__global__ __launch_bounds__(128) void lnred_k(
    const float* __restrict__ x, const float* __restrict__ w,
    const float* __restrict__ b, const float* __restrict__ rw,
    const float* __restrict__ rb, ushort* __restrict__ hgb,
    float* __restrict__ z)
{
    int row = blockIdx.x;
    int tid = threadIdx.x;
    const float* xr = x + (size_t)row * D_;
    __shared__ float hrow[D_];
    __shared__ float parts[R_][5];
    float v[5];
    float sum = 0.f, sumsq = 0.f;
    #pragma unroll
    for (int t = 0; t < 5; ++t) {
        v[t] = xr[tid + t * 128];
        sum += v[t]; sumsq += v[t] * v[t];
    }
    #pragma unroll
    for (int off = 32; off > 0; off >>= 1) {
        sum += __shfl_down(sum, off);
        sumsq += __shfl_down(sumsq, off);
    }
    __shared__ float s0[2], s1[2];
    if ((tid & 63) == 0) { s0[tid >> 6] = sum; s1[tid >> 6] = sumsq; }
    __syncthreads();
    float m = (s0[0] + s0[1]) * (1.0f / D_);
    float var = (s1[0] + s1[1]) * (1.0f / D_) - m * m;
    float inv = rsqrtf(var + LN_EPS_);
    #pragma unroll
    for (int t = 0; t < 5; ++t) {
        int d = tid + t * 128;
        float o = (v[t] - m) * inv * w[d] + b[d];
        hgb[(size_t)row * (2 * D_) + d] = f2b(o);
        hrow[d] = o;
    }
    __syncthreads();
    if (tid < 120) {
        int c = tid / 5, ch = tid - c * 5;
        const float4* hv = (const float4*)(hrow + ch * 128);
        const float4* wv = (const float4*)(rw + (size_t)c * D_ + ch * 128);
        float p = 0.f;
        #pragma unroll 8
        for (int k = 0; k < 32; ++k) {
            float4 a = hv[k], bb = wv[k];
            p += a.x * bb.x + a.y * bb.y + a.z * bb.z + a.w * bb.w;
        }
        parts[c][ch] = p;
    }
    __syncthreads();
    if (tid < R_) {
        float s = parts[tid][0] + parts[tid][1] + parts[tid][2] + parts[tid][3] + parts[tid][4];
        z[(size_t)row * R_ + tid] = s + rb[tid];
    }
}

// ---------------------------------------------------------------------------
__global__ __launch_bounds__(256) void embed_k(
    const int* __restrict__ ids, const float* __restrict__ tok,
    const float* __restrict__ pos, float* __restrict__ x)
{
    int idx = blockIdx.x * 256 + threadIdx.x;
    if (idx >= M_ * D_) return;
    int row = idx / D_;
    int d = idx - row * D_;
    int l = row & (L_ - 1);
    x[idx] = tok[(size_t)ids[row] * D_ + d] + pos[(size_t)l * D_ + d];
}

__global__ __launch_bounds__(256) void cvt_k(
    const float* __restrict__ src, ushort* __restrict__ dst, int n)
{
    int idx = blockIdx.x * 256 + threadIdx.x;
    if (idx < n) dst[idx] = f2b(src[idx]);
}

// per-layer weight conversion (gp1 padded 276->288, gp2, gate, fc1, fc2)
#define WC_G1  73728
#define WC_G2  (WC_G1 + 163840)
#define WC_GT  (WC_G2 + 819200)
#define WC_F1  (WC_GT + 1638400)
#define WC_F2  (WC_F1 + 1638400)
__device__ __forceinline__ void wconv_body(
    int idx, const float* g1, const float* g2, const float* gt,
    const float* f1, const float* f2, ushort* wb)
{
    if (idx < WC_G1) {
        int row = idx / PLUP_, c = idx - row * PLUP_;
        wb[idx] = (c < PLU_) ? f2b(g1[row * PLU_ + c]) : (ushort)0;
    } else if (idx < WC_G2) {
        wb[idx] = f2b(g2[idx - WC_G1]);
    } else if (idx < WC_GT) {
        wb[idx] = f2b(gt[idx - WC_G2]);
    } else if (idx < WC_F1) {
        wb[idx] = f2b(f1[idx - WC_GT]);
    } else if (idx < WC_F2) {
        wb[idx] = f2b(f2[idx - WC_F1]);
    }
}

__global__ __launch_bounds__(256) void wconv_k(
    const float* __restrict__ g1, const float* __restrict__ g2,
    const float* __restrict__ gt, const float* __restrict__ f1,
    const float* __restrict__ f2, ushort* __restrict__ wb)
{
    int idx = blockIdx.x * 256 + threadIdx.x;
    wconv_body(idx, g1, g2, gt, f1, f2, wb);
}

__global__ __launch_bounds__(256) void wconv_all_k(
    const float* __restrict__ g1, const float* __restrict__ g2,
    const float* __restrict__ gt, const float* __restrict__ f1,
    const float* __restrict__ f2, ushort* __restrict__ wb_all)
{
    int l = blockIdx.y;
    int idx = blockIdx.x * 256 + threadIdx.x;
    wconv_body(idx,
               g1 + (size_t)l * DG_ * PLU_, g2 + (size_t)l * D_ * DG_,
               gt + (size_t)l * D_ * 2 * D_, f1 + (size_t)l * DF_ * D_,
               f2 + (size_t)l * D_ * DF_, wb_all + (size_t)l * WC_F2);
}

// ---------------------------------------------------------------------------
__global__ __launch_bounds__(128) void ln_k(
    const float* __restrict__ x, const float* __restrict__ w,
    const float* __restrict__ b, float* __restrict__ outf,
    ushort* __restrict__ outb, int bstride)
{
    int row = blockIdx.x;
    int tid = threadIdx.x;
    const float* xr = x + (size_t)row * D_;
    float v[5];
    float sum = 0.f, sumsq = 0.f;
    #pragma unroll
    for (int t = 0; t < 5; ++t) {
        v[t] = xr[tid + t * 128];
        sum += v[t]; sumsq += v[t] * v[t];
    }
    #pragma unroll
    for (int off = 32; off > 0; off >>= 1) {
        sum += __shfl_down(sum, off);
        sumsq += __shfl_down(sumsq, off);
    }
    __shared__ float s0[2], s1[2];
    if ((tid & 63) == 0) { s0[tid >> 6] = sum; s1[tid >> 6] = sumsq; }
    __syncthreads();
    float m = (s0[0] + s0[1]) * (1.0f / D_);
    float var = (s1[0] + s1[1]) * (1.0f / D_) - m * m;
    float inv = rsqrtf(var + LN_EPS_);
    #pragma unroll
    for (int t = 0; t < 5; ++t) {
        int d = tid + t * 128;
        float o = (v[t] - m) * inv * w[d] + b[d];
        if (outf) outf[(size_t)row * D_ + d] = o;
        if (outb) outb[(size_t)row * bstride + d] = f2b(o);
    }
}

// ---------------------------------------------------------------------------
__global__ __launch_bounds__(128) void plucker7_k(
    const float* __restrict__ z, ushort* __restrict__ pb)
{
    int oi = blockIdx.y;
    int delta = 1 << oi;
    int row = blockIdx.x;
    int l = row & (L_ - 1);
    int tid = threadIdx.x;
    ushort* out = pb + ((size_t)oi * M_ + row) * PLUP_;
    if (l < delta) {
        for (int idx = tid; idx < PLUP_; idx += 128) out[idx] = 0;
        return;
    }
    __shared__ float zc[R_], zp[R_];
    if (tid < R_) {
        zc[tid] = z[(size_t)row * R_ + tid];
        zp[tid] = z[(size_t)(row - delta) * R_ + tid];
    }
    __syncthreads();
    float vals[3];
    float ss = 0.f;
    #pragma unroll
    for (int t = 0; t < 3; ++t) {
        int idx = tid + t * 128;
        float val = 0.f;
        if (idx < PLU_) {
            int i = 0, rem = idx;
            while (rem >= 23 - i) { rem -= 23 - i; ++i; }
            int j = i + 1 + rem;
            val = zp[i] * zc[j] - zp[j] * zc[i];
        }
        vals[t] = val;
        ss += val * val;
    }
    #pragma unroll
    for (int off = 32; off > 0; off >>= 1) ss += __shfl_down(ss, off);
    __shared__ float wsum[2];
    if ((tid & 63) == 0) wsum[tid >> 6] = ss;
    __syncthreads();
    float inv = 1.0f / fmaxf(sqrtf(wsum[0] + wsum[1]), EPS_);
    #pragma unroll
    for (int t = 0; t < 3; ++t) {
        int idx = tid + t * 128;
        if (idx < PLUP_) out[idx] = (idx < PLU_) ? f2b(vals[t] * inv) : (ushort)0;
    }
}

// ---------------------------------------------------------------------------
static void mg128(int epi, const ushort* A, const ushort* W, const float* bias,
                  float* Cf, ushort* Cb, int M, int N, int K, hipStream_t s)
{
    dim3 grid(M / 128, (N + 127) / 128), block(256);
    if (epi == 0)      mgemm128_k<0><<<grid, block, 0, s>>>(A, W, bias, Cf, Cb, M, N, K);
    else if (epi == 1) mgemm128_k<1><<<grid, block, 0, s>>>(A, W, bias, Cf, Cb, M, N, K);
    else               mgemm128_k<4><<<grid, block, 0, s>>>(A, W, bias, Cf, Cb, M, N, K);
}

static void mg12864(int epi, const ushort* A, const ushort* W, const float* bias,
                    float* Cf, const ushort* hg, ushort* ub,
                    int M, int N, int K, hipStream_t s)
{
    dim3 grid(M / 128, N / 64), block(256);
    if (epi == 2)      mgemm12864_k<2><<<grid, block, 0, s>>>(A, W, bias, Cf, hg, ub, M, N, K);
    else if (epi == 3) mgemm12864_k<3><<<grid, block, 0, s>>>(A, W, bias, Cf, hg, ub, M, N, K);
    else               mgemm12864_k<5><<<grid, block, 0, s>>>(A, W, bias, Cf, hg, ub, M, N, K);
}

extern "C" void kernel_launch(void* const* d_in, const int* in_sizes, int n_in,
                              void* d_out, int out_size, void* d_ws, size_t ws_size,
                              hipStream_t stream)
{
    const int*   ids   = (const int*)d_in[0];
    const float* tok   = (const float*)d_in[1];
    const float* pos   = (const float*)d_in[2];
    const float* ln1w  = (const float*)d_in[3];
    const float* ln1b  = (const float*)d_in[4];
    const float* redw  = (const float*)d_in[5];
    const float* redb  = (const float*)d_in[6];
    const float* gp1w  = (const float*)d_in[7];
    const float* gp1b  = (const float*)d_in[8];
    const float* gp2w  = (const float*)d_in[9];
    const float* gp2b  = (const float*)d_in[10];
    const float* gatew = (const float*)d_in[11];
    const float* gateb = (const float*)d_in[12];
    const float* ln2w  = (const float*)d_in[13];
    const float* ln2b  = (const float*)d_in[14];
    const float* fc1w  = (const float*)d_in[15];
    const float* fc1b  = (const float*)d_in[16];
    const float* fc2w  = (const float*)d_in[17];
    const float* fc2b  = (const float*)d_in[18];
    const float* fnw   = (const float*)d_in[19];
    const float* fnb   = (const float*)d_in[20];
    float* out = (float*)d_out;

    const size_t MD = (size_t)M_ * D_;
    float* ws = (float*)d_ws;
    float* x = ws;                       // MD f32
    float* z = x + MD;                   // M_*R_ f32
    ushort* pb    = (ushort*)(z + (size_t)M_ * R_);       // 7*M_*288
    ushort* c1b   = pb + (size_t)7 * M_ * PLUP_;          // 7*M_*256
    ushort* crb   = c1b + (size_t)7 * M_ * DG_;           // M_*256
    ushort* hgb   = crb + (size_t)M_ * DG_;               // M_*1280
    ushort* h2b   = hgb + (size_t)M_ * 2 * D_;            // M_*640
    ushort* ffb   = h2b + MD;                             // M_*2560
    ushort* xnb   = ffb + (size_t)M_ * DF_;               // M_*640
    ushort* tokb  = xnb + MD;                             // V_*640
    ushort* wb    = tokb + (size_t)V_ * D_;               // WC_F2 (or x16)

    const size_t base_bytes = (size_t)((char*)wb - (char*)d_ws);
    const bool all_w = ws_size >= base_bytes + (size_t)NL_ * WC_F2 * 2;

    const int ELT_GRID = (M_ * D_ + 255) / 256;
    const int WC_GRID = (WC_F2 + 255) / 256;

    embed_k<<<ELT_GRID, 256, 0, stream>>>(ids, tok, pos, x);
    cvt_k<<<(V_ * D_ + 255) / 256, 256, 0, stream>>>(tok, tokb, V_ * D_);
    if (all_w)
        wconv_all_k<<<dim3(WC_GRID, NL_), 256, 0, stream>>>(gp1w, gp2w, gatew, fc1w, fc2w, wb);

    for (int l = 0; l < NL_; ++l) {
        const ushort* wbl = all_w ? wb + (size_t)l * WC_F2 : wb;
        if (!all_w)
            wconv_k<<<WC_GRID, 256, 0, stream>>>(
                gp1w + (size_t)l * DG_ * PLU_, gp2w + (size_t)l * D_ * DG_,
                gatew + (size_t)l * D_ * 2 * D_, fc1w + (size_t)l * DF_ * D_,
                fc2w + (size_t)l * D_ * DF_, wb);
        lnred_k<<<M_, 128, 0, stream>>>(x, ln1w + (size_t)l * D_, ln1b + (size_t)l * D_,
                                        redw + (size_t)l * R_ * D_, redb + (size_t)l * R_,
                                        hgb, z);
        plucker7_k<<<dim3(M_, 7), 128, 0, stream>>>(z, pb);
        mg128(1, pb, wbl, gp1b + (size_t)l * DG_, nullptr, c1b, 7 * M_, DG_, PLUP_, stream);
        credsum_k<<<(M_ * DG_ / 4 + 255) / 256, 256, 0, stream>>>(c1b, crb);
        // gp2 on M rows (linearity fusion): g -> bf16 into hgb[.,D..2D)
        mg12864(5, crb, wbl + WC_G1, gp2b + (size_t)l * D_, nullptr, nullptr, hgb,
                M_, D_, DG_, stream);
        // gate fused with x-update; h,g read from bf16 hgb
        mg12864(2, hgb, wbl + WC_G2, gateb + (size_t)l * D_, x, hgb, nullptr,
                M_, D_, 2 * D_, stream);
        ln_k<<<M_, 128, 0, stream>>>(x, ln2w + (size_t)l * D_, ln2b + (size_t)l * D_,
                                     nullptr, h2b, D_);
        mg128(1, h2b, wbl + WC_GT, fc1b + (size_t)l * DF_, nullptr, ffb, M_, DF_, D_, stream);
        mg12864(3, ffb, wbl + WC_F1, fc2b + (size_t)l * D_, x, nullptr, nullptr,
                M_, D_, DF_, stream);
    }
    ln_k<<<M_, 128, 0, stream>>>(x, fnw, fnb, nullptr, xnb, D_);
    mg128(0, xnb, tokb, nullptr, out, nullptr, M_, V_, D_, stream);
}

// Round 11
// 4047.448 us; speedup vs baseline: 1.3078x; 1.0077x over previous
//
#include <hip/hip_runtime.h>
#include <cmath>

#define V_ 50257
#define D_ 640
#define NL_ 16
#define DF_ 2560
#define R_ 24
#define DG_ 256
#define PLU_ 276
#define PLUP_ 288
#define B_ 4
#define L_ 1024
#define M_ (B_*L_)
#define EPS_ 1e-6f
#define LN_EPS_ 1e-5f

typedef __bf16 bf16x8 __attribute__((ext_vector_type(8)));
typedef float f32x4 __attribute__((ext_vector_type(4)));

__device__ __forceinline__ float gelu_exact(float x) {
    return 0.5f * x * (1.0f + erff(x * 0.70710678118654752f));
}
__device__ __forceinline__ float sigmoid_f(float x) {
    return 1.0f / (1.0f + expf(-x));
}
__device__ __forceinline__ ushort f2b(float f) {
    union { float f; unsigned u; } v; v.f = f;
    unsigned u = v.u;
    return (ushort)((u + 0x7FFFu + ((u >> 16) & 1u)) >> 16);
}
__device__ __forceinline__ float b2f(ushort b) {
    union { unsigned u; float f; } v; v.u = ((unsigned)b) << 16;
    return v.f;
}

#define GLOAD16(gptr, lptr) \
    __builtin_amdgcn_global_load_lds((const __attribute__((address_space(1))) void*)(gptr), \
                                     (__attribute__((address_space(3))) void*)(lptr), 16, 0, 0)

// LEDGER:
// R4: XCD remap regressed (lm_head FETCH 288->830MB). Natural blockIdx order.
// R2->R3: LDS XOR-swizzle: SQ_LDS_BANK_CONFLICT 3.2e7 -> 0. Keep.
// R6+R9: 3-stage counted-vmcnt pipeline FAILED correctness TWICE (absmax
//     0.57 / 0.65; raw s_barrier does not wait lgkmcnt -> DMA overwrites
//     issued-but-unserviced ds_reads; rule #18 class). FORBIDDEN.
//     Verified schedule: 2-phase {STAGE(next); ds_read+MFMA(cur); vmcnt(0);
//     s_barrier} (passed R4,R5,R7,R8,R10).
// R7: coalesced LDS-transpose f32 epilogue: lm_head 554 -> <480us. Keep.
// R8: gp2 linearity fusion (credsum before gp2, 7x FLOP cut): 4686->4191.
// R10: gate epilogue reads h/g from bf16 hgb (f32 h/g deleted): 4191->4079.
// R11: lm_head -> 256x128 tile (8 waves; in-block W-panel reuse halves W
//     traffic) + NONTEMPORAL f32 stores (823MB streaming writes bypass L2,
//     stop evicting W tiles). Same 2-phase sync skeleton.

// ---------------------------------------------------------------------------
// 128x128 tile, 4 waves (2x2), each wave 64x64 = 4x4 frags of 16x16x32.
// 2-phase double-buffered pipeline (verified).
// EPI: 1 = gelu->bf16; 4 = bf16
// ---------------------------------------------------------------------------
#define AS_(b) (shmem + (b) * 4096)
#define BS_(b) (shmem + 8192 + (b) * 4096)
#define STAGE128(b, k0) do { \
    GLOAD16(A + (size_t)(bm + w * 32 + srow) * (size_t)K + ((k0) + scol), AS_(b) + (w * 32) * 32); \
    GLOAD16(A + (size_t)(bm + w * 32 + 16 + srow) * (size_t)K + ((k0) + scol), AS_(b) + (w * 32 + 16) * 32); \
    int rb0_ = bn + w * 32 + srow;      if (rb0_ > N - 1) rb0_ = N - 1; \
    int rb1_ = bn + w * 32 + 16 + srow; if (rb1_ > N - 1) rb1_ = N - 1; \
    GLOAD16(W + (size_t)rb0_ * (size_t)K + ((k0) + scol), BS_(b) + (w * 32) * 32); \
    GLOAD16(W + (size_t)rb1_ * (size_t)K + ((k0) + scol), BS_(b) + (w * 32 + 16) * 32); \
} while (0)

template<int EPI>
__global__ __launch_bounds__(256) void mgemm128_k(
    const ushort* __restrict__ A, const ushort* __restrict__ W,
    const float* __restrict__ bias, float* __restrict__ Cf,
    ushort* __restrict__ Cb, int M, int N, int K)
{
    __shared__ ushort shmem[16384];   // As[2][4096] | Bs[2][4096]
    const int tid = threadIdx.x;
    const int lane = tid & 63;
    const int w = tid >> 6;
    const int wr = w >> 1, wc = w & 1;
    const int lr = lane & 15, lk = lane >> 4;
    const int bm = blockIdx.x * 128, bn = blockIdx.y * 128;
    const int srow = lane >> 2;
    const int scol = (((lane & 3) ^ ((srow >> 1) & 3)) * 8);

    f32x4 acc[4][4] = {};
    const int nt = K >> 5;

    STAGE128(0, 0);
    asm volatile("s_waitcnt vmcnt(0)" ::: "memory");
    __builtin_amdgcn_s_barrier();

    int cur = 0;
    for (int t = 0; t < nt; ++t) {
        if (t + 1 < nt) { STAGE128(cur ^ 1, (t + 1) * 32); }
        bf16x8 af[4], bfr[4];
        #pragma unroll
        for (int m = 0; m < 4; ++m) {
            int rr = wr * 64 + m * 16 + lr;
            af[m] = *reinterpret_cast<const bf16x8*>(&AS_(cur)[rr * 32 + ((lk ^ ((rr >> 1) & 3)) * 8)]);
        }
        #pragma unroll
        for (int n = 0; n < 4; ++n) {
            int rr = wc * 64 + n * 16 + lr;
            bfr[n] = *reinterpret_cast<const bf16x8*>(&BS_(cur)[rr * 32 + ((lk ^ ((rr >> 1) & 3)) * 8)]);
        }
        #pragma unroll
        for (int m = 0; m < 4; ++m)
            #pragma unroll
            for (int n = 0; n < 4; ++n)
                acc[m][n] = __builtin_amdgcn_mfma_f32_16x16x32_bf16(af[m], bfr[n], acc[m][n], 0, 0, 0);
        asm volatile("s_waitcnt vmcnt(0)" ::: "memory");
        __builtin_amdgcn_s_barrier();
        cur ^= 1;
    }

    #pragma unroll
    for (int n = 0; n < 4; ++n) {
        int col = bn + wc * 64 + n * 16 + lr;
        if (col >= N) continue;
        float bsv = bias ? bias[col] : 0.0f;
        #pragma unroll
        for (int m = 0; m < 4; ++m) {
            #pragma unroll
            for (int r4 = 0; r4 < 4; ++r4) {
                int row = bm + wr * 64 + m * 16 + lk * 4 + r4;
                float o = acc[m][n][r4] + bsv;
                size_t idx = (size_t)row * N + col;
                if (EPI == 1) Cb[idx] = f2b(gelu_exact(o));
                else          Cb[idx] = f2b(o);
            }
        }
    }
}

// ---------------------------------------------------------------------------
// lm_head kernel: 256x128 tile, 8 waves (4x2), 512 threads. Same verified
// 2-phase pipeline (3 loads/wave/K-step; vmcnt(0)+barrier). Coalesced f32
// epilogue via per-wave LDS transpose, NONTEMPORAL stores (write-streaming,
// never re-read -> keep W tiles in L2).
// ---------------------------------------------------------------------------
#define AS2_(b) (shmem + (b) * 8192)
#define BS2_(b) (shmem + 16384 + (b) * 4096)
#define STAGE256(b, k0) do { \
    GLOAD16(A + (size_t)(bm + w * 32 + srow) * (size_t)K + ((k0) + scol), AS2_(b) + (w * 32) * 32); \
    GLOAD16(A + (size_t)(bm + w * 32 + 16 + srow) * (size_t)K + ((k0) + scol), AS2_(b) + (w * 32 + 16) * 32); \
    int rb_ = bn + w * 16 + srow; if (rb_ > N - 1) rb_ = N - 1; \
    GLOAD16(W + (size_t)rb_ * (size_t)K + ((k0) + scol), BS2_(b) + (w * 16) * 32); \
} while (0)

__global__ __launch_bounds__(512) void mgemm256nt_k(
    const ushort* __restrict__ A, const ushort* __restrict__ W,
    float* __restrict__ Cf, int M, int N, int K)
{
    __shared__ ushort shmem[24576];   // As[2][8192] | Bs[2][4096] = 48KB
    const int tid = threadIdx.x;
    const int lane = tid & 63;
    const int w = tid >> 6;           // 0..7
    const int wr = w >> 1, wc = w & 1;
    const int lr = lane & 15, lk = lane >> 4;
    const int bm = blockIdx.x * 256, bn = blockIdx.y * 128;
    const int srow = lane >> 2;
    const int scol = (((lane & 3) ^ ((srow >> 1) & 3)) * 8);

    f32x4 acc[4][4] = {};
    const int nt = K >> 5;

    STAGE256(0, 0);
    asm volatile("s_waitcnt vmcnt(0)" ::: "memory");
    __builtin_amdgcn_s_barrier();

    int cur = 0;
    for (int t = 0; t < nt; ++t) {
        if (t + 1 < nt) { STAGE256(cur ^ 1, (t + 1) * 32); }
        bf16x8 af[4], bfr[4];
        #pragma unroll
        for (int m = 0; m < 4; ++m) {
            int rr = wr * 64 + m * 16 + lr;    // 0..255
            af[m] = *reinterpret_cast<const bf16x8*>(&AS2_(cur)[rr * 32 + ((lk ^ ((rr >> 1) & 3)) * 8)]);
        }
        #pragma unroll
        for (int n = 0; n < 4; ++n) {
            int rr = wc * 64 + n * 16 + lr;    // 0..127
            bfr[n] = *reinterpret_cast<const bf16x8*>(&BS2_(cur)[rr * 32 + ((lk ^ ((rr >> 1) & 3)) * 8)]);
        }
        #pragma unroll
        for (int m = 0; m < 4; ++m)
            #pragma unroll
            for (int n = 0; n < 4; ++n)
                acc[m][n] = __builtin_amdgcn_mfma_f32_16x16x32_bf16(af[m], bfr[n], acc[m][n], 0, 0, 0);
        asm volatile("s_waitcnt vmcnt(0)" ::: "memory");
        __builtin_amdgcn_s_barrier();
        cur ^= 1;
    }

    // Coalesced nontemporal f32 epilogue: per-wave 16x64 LDS transpose,
    // each store writes 256B contiguous; nt flag bypasses L2.
    float* lds_f = (float*)shmem;
    const int wbase = w * (16 * 68);           // 8 waves x 1088 f32 = 34.8KB
    #pragma unroll
    for (int m = 0; m < 4; ++m) {
        #pragma unroll
        for (int n = 0; n < 4; ++n) {
            #pragma unroll
            for (int r4 = 0; r4 < 4; ++r4)
                lds_f[wbase + (lk * 4 + r4) * 68 + n * 16 + lr] = acc[m][n][r4];
        }
        __syncthreads();
        #pragma unroll
        for (int r = 0; r < 16; ++r) {
            int row = bm + wr * 64 + m * 16 + r;
            int col = bn + wc * 64 + lane;
            float v = lds_f[wbase + r * 68 + lane];
            if (col < N)
                __builtin_nontemporal_store(v, &Cf[(size_t)row * N + col]);
        }
        __syncthreads();
    }
}

// ---------------------------------------------------------------------------
// 128x64 tile, 4 waves, wave 64x32 = 4x2 frags. Verified 2-phase pipeline.
// EPI==2: alpha=sigmoid(o); x += a*h + (1-a)*g with h,g read from bf16 hg.
// EPI==3: Cf += o.
// EPI==5: g-write after credsum: l==0 -> 0; bf16 into hg at D+col.
// ---------------------------------------------------------------------------
#define STAGE12864(b, k0) do { \
    GLOAD16(A + (size_t)(bm + w * 16 + srow) * (size_t)K + ((k0) + scol), &As[b][(w * 16) * 32]); \
    GLOAD16(A + (size_t)(bm + 64 + w * 16 + srow) * (size_t)K + ((k0) + scol), &As[b][(64 + w * 16) * 32]); \
    GLOAD16(W + (size_t)(bn + w * 16 + srow) * (size_t)K + ((k0) + scol), &Bs[b][(w * 16) * 32]); \
} while (0)

template<int EPI>
__global__ __launch_bounds__(256) void mgemm12864_k(
    const ushort* __restrict__ A, const ushort* __restrict__ W,
    const float* __restrict__ bias, float* __restrict__ Cf,
    const ushort* __restrict__ hg, ushort* __restrict__ ub,
    int M, int N, int K)
{
    __shared__ ushort As[2][128 * 32];
    __shared__ ushort Bs[2][64 * 32];
    const int tid = threadIdx.x;
    const int lane = tid & 63;
    const int w = tid >> 6;
    const int wr = w >> 1, wc = w & 1;
    const int lr = lane & 15, lk = lane >> 4;
    const int bm = blockIdx.x * 128, bn = blockIdx.y * 64;
    const int srow = lane >> 2;
    const int scol = (((lane & 3) ^ ((srow >> 1) & 3)) * 8);

    f32x4 acc[4][2] = {};
    const int nt = K >> 5;

    STAGE12864(0, 0);
    asm volatile("s_waitcnt vmcnt(0)" ::: "memory");
    __builtin_amdgcn_s_barrier();

    int cur = 0;
    for (int t = 0; t < nt; ++t) {
        if (t + 1 < nt) { STAGE12864(cur ^ 1, (t + 1) * 32); }
        bf16x8 af[4], bfr[2];
        #pragma unroll
        for (int m = 0; m < 4; ++m) {
            int rr = wr * 64 + m * 16 + lr;
            af[m] = *reinterpret_cast<const bf16x8*>(&As[cur][rr * 32 + ((lk ^ ((rr >> 1) & 3)) * 8)]);
        }
        #pragma unroll
        for (int n = 0; n < 2; ++n) {
            int rr = wc * 32 + n * 16 + lr;
            bfr[n] = *reinterpret_cast<const bf16x8*>(&Bs[cur][rr * 32 + ((lk ^ ((rr >> 1) & 3)) * 8)]);
        }
        #pragma unroll
        for (int m = 0; m < 4; ++m)
            #pragma unroll
            for (int n = 0; n < 2; ++n)
                acc[m][n] = __builtin_amdgcn_mfma_f32_16x16x32_bf16(af[m], bfr[n], acc[m][n], 0, 0, 0);
        asm volatile("s_waitcnt vmcnt(0)" ::: "memory");
        __builtin_amdgcn_s_barrier();
        cur ^= 1;
    }

    #pragma unroll
    for (int n = 0; n < 2; ++n) {
        int col = bn + wc * 32 + n * 16 + lr;
        float bsv = bias ? bias[col] : 0.0f;
        #pragma unroll
        for (int m = 0; m < 4; ++m) {
            #pragma unroll
            for (int r4 = 0; r4 < 4; ++r4) {
                int row = bm + wr * 64 + m * 16 + lk * 4 + r4;
                float o = acc[m][n][r4] + bsv;
                size_t idx = (size_t)row * N + col;
                if (EPI == 2) {
                    float a = sigmoid_f(o);
                    float hv = b2f(hg[(size_t)row * (2 * D_) + col]);
                    float gv = b2f(hg[(size_t)row * (2 * D_) + D_ + col]);
                    Cf[idx] = Cf[idx] + a * hv + (1.0f - a) * gv;
                } else if (EPI == 3) {
                    Cf[idx] += o;
                } else if (EPI == 5) {
                    if ((row & (L_ - 1)) == 0) o = 0.0f;   // count==0 rows: g = 0
                    ub[(size_t)row * (2 * D_) + D_ + col] = f2b(o);
                }
            }
        }
    }
}

// ---------------------------------------------------------------------------
// credsum: cravg[row, c] = (sum over valid deltas of c1[d,row,c]) / count.
// ---------------------------------------------------------------------------
__global__ __launch_bounds__(256) void credsum_k(
    const ushort* __restrict__ c1b, ushort* __restrict__ crb)
{
    int idx4 = blockIdx.x * 256 + threadIdx.x;
    if (idx4 >= M_ * DG_ / 4) return;
    int idx = idx4 * 4;
    int row = idx / DG_;
    int l = row & (L_ - 1);
    float s0 = 0.f, s1 = 0.f, s2 = 0.f, s3 = 0.f;
    int c = 0;
    #pragma unroll
    for (int oi = 0; oi < 7; ++oi) {
        if (l >= (1 << oi)) {
            ushort4 v = *reinterpret_cast<const ushort4*>(c1b + (size_t)oi * M_ * DG_ + idx);
            s0 += b2f(v.x); s1 += b2f(v.y); s2 += b2f(v.z); s3 += b2f(v.w);
            ++c;
        }
    }
    float inv = 1.0f / (float)max(c, 1);
    ushort4 o;
    o.x = f2b(s0 * inv); o.y = f2b(s1 * inv); o.z = f2b(s2 * inv); o.w = f2b(s3 * inv);
    *reinterpret_cast<ushort4*>(crb + idx) = o;
}

// ---------------------------------------------------------------------------
// Fused LN1 + red projection: one block (128 thr) per row.
// ---------------------------------------------------------------------------
__global__ __launch_bounds__(128) void lnred_k(
    const float* __restrict__ x, const float* __restrict__ w,
    const float* __restrict__ b, const float* __restrict__ rw,
    const float* __restrict__ rb, ushort* __restrict__ hgb,
    float* __restrict__ z)
{
    int row = blockIdx.x;
    int tid = threadIdx.x;
    const float* xr = x + (size_t)row * D_;
    __shared__ float hrow[D_];
    __shared__ float parts[R_][5];
    float v[5];
    float sum = 0.f, sumsq = 0.f;
    #pragma unroll
    for (int t = 0; t < 5; ++t) {
        v[t] = xr[tid + t * 128];
        sum += v[t]; sumsq += v[t] * v[t];
    }
    #pragma unroll
    for (int off = 32; off > 0; off >>= 1) {
        sum += __shfl_down(sum, off);
        sumsq += __shfl_down(sumsq, off);
    }
    __shared__ float s0[2], s1[2];
    if ((tid & 63) == 0) { s0[tid >> 6] = sum; s1[tid >> 6] = sumsq; }
    __syncthreads();
    float m = (s0[0] + s0[1]) * (1.0f / D_);
    float var = (s1[0] + s1[1]) * (1.0f / D_) - m * m;
    float inv = rsqrtf(var + LN_EPS_);
    #pragma unroll
    for (int t = 0; t < 5; ++t) {
        int d = tid + t * 128;
        float o = (v[t] - m) * inv * w[d] + b[d];
        hgb[(size_t)row * (2 * D_) + d] = f2b(o);
        hrow[d] = o;
    }
    __syncthreads();
    if (tid < 120) {
        int c = tid / 5, ch = tid - c * 5;
        const float4* hv = (const float4*)(hrow + ch * 128);
        const float4* wv = (const float4*)(rw + (size_t)c * D_ + ch * 128);
        float p = 0.f;
        #pragma unroll 8
        for (int k = 0; k < 32; ++k) {
            float4 a = hv[k], bb = wv[k];
            p += a.x * bb.x + a.y * bb.y + a.z * bb.z + a.w * bb.w;
        }
        parts[c][ch] = p;
    }
    __syncthreads();
    if (tid < R_) {
        float s = parts[tid][0] + parts[tid][1] + parts[tid][2] + parts[tid][3] + parts[tid][4];
        z[(size_t)row * R_ + tid] = s + rb[tid];
    }
}

// ---------------------------------------------------------------------------
__global__ __launch_bounds__(256) void embed_k(
    const int* __restrict__ ids, const float* __restrict__ tok,
    const float* __restrict__ pos, float* __restrict__ x)
{
    int idx = blockIdx.x * 256 + threadIdx.x;
    if (idx >= M_ * D_) return;
    int row = idx / D_;
    int d = idx - row * D_;
    int l = row & (L_ - 1);
    x[idx] = tok[(size_t)ids[row] * D_ + d] + pos[(size_t)l * D_ + d];
}

__global__ __launch_bounds__(256) void cvt_k(
    const float* __restrict__ src, ushort* __restrict__ dst, int n)
{
    int idx = blockIdx.x * 256 + threadIdx.x;
    if (idx < n) dst[idx] = f2b(src[idx]);
}

// per-layer weight conversion (gp1 padded 276->288, gp2, gate, fc1, fc2)
#define WC_G1  73728
#define WC_G2  (WC_G1 + 163840)
#define WC_GT  (WC_G2 + 819200)
#define WC_F1  (WC_GT + 1638400)
#define WC_F2  (WC_F1 + 1638400)
__device__ __forceinline__ void wconv_body(
    int idx, const float* g1, const float* g2, const float* gt,
    const float* f1, const float* f2, ushort* wb)
{
    if (idx < WC_G1) {
        int row = idx / PLUP_, c = idx - row * PLUP_;
        wb[idx] = (c < PLU_) ? f2b(g1[row * PLU_ + c]) : (ushort)0;
    } else if (idx < WC_G2) {
        wb[idx] = f2b(g2[idx - WC_G1]);
    } else if (idx < WC_GT) {
        wb[idx] = f2b(gt[idx - WC_G2]);
    } else if (idx < WC_F1) {
        wb[idx] = f2b(f1[idx - WC_GT]);
    } else if (idx < WC_F2) {
        wb[idx] = f2b(f2[idx - WC_F1]);
    }
}

__global__ __launch_bounds__(256) void wconv_k(
    const float* __restrict__ g1, const float* __restrict__ g2,
    const float* __restrict__ gt, const float* __restrict__ f1,
    const float* __restrict__ f2, ushort* __restrict__ wb)
{
    int idx = blockIdx.x * 256 + threadIdx.x;
    wconv_body(idx, g1, g2, gt, f1, f2, wb);
}

__global__ __launch_bounds__(256) void wconv_all_k(
    const float* __restrict__ g1, const float* __restrict__ g2,
    const float* __restrict__ gt, const float* __restrict__ f1,
    const float* __restrict__ f2, ushort* __restrict__ wb_all)
{
    int l = blockIdx.y;
    int idx = blockIdx.x * 256 + threadIdx.x;
    wconv_body(idx,
               g1 + (size_t)l * DG_ * PLU_, g2 + (size_t)l * D_ * DG_,
               gt + (size_t)l * D_ * 2 * D_, f1 + (size_t)l * DF_ * D_,
               f2 + (size_t)l * D_ * DF_, wb_all + (size_t)l * WC_F2);
}

// ---------------------------------------------------------------------------
__global__ __launch_bounds__(128) void ln_k(
    const float* __restrict__ x, const float* __restrict__ w,
    const float* __restrict__ b, float* __restrict__ outf,
    ushort* __restrict__ outb, int bstride)
{
    int row = blockIdx.x;
    int tid = threadIdx.x;
    const float* xr = x + (size_t)row * D_;
    float v[5];
    float sum = 0.f, sumsq = 0.f;
    #pragma unroll
    for (int t = 0; t < 5; ++t) {
        v[t] = xr[tid + t * 128];
        sum += v[t]; sumsq += v[t] * v[t];
    }
    #pragma unroll
    for (int off = 32; off > 0; off >>= 1) {
        sum += __shfl_down(sum, off);
        sumsq += __shfl_down(sumsq, off);
    }
    __shared__ float s0[2], s1[2];
    if ((tid & 63) == 0) { s0[tid >> 6] = sum; s1[tid >> 6] = sumsq; }
    __syncthreads();
    float m = (s0[0] + s0[1]) * (1.0f / D_);
    float var = (s1[0] + s1[1]) * (1.0f / D_) - m * m;
    float inv = rsqrtf(var + LN_EPS_);
    #pragma unroll
    for (int t = 0; t < 5; ++t) {
        int d = tid + t * 128;
        float o = (v[t] - m) * inv * w[d] + b[d];
        if (outf) outf[(size_t)row * D_ + d] = o;
        if (outb) outb[(size_t)row * bstride + d] = f2b(o);
    }
}

// ---------------------------------------------------------------------------
__global__ __launch_bounds__(128) void plucker7_k(
    const float* __restrict__ z, ushort* __restrict__ pb)
{
    int oi = blockIdx.y;
    int delta = 1 << oi;
    int row = blockIdx.x;
    int l = row & (L_ - 1);
    int tid = threadIdx.x;
    ushort* out = pb + ((size_t)oi * M_ + row) * PLUP_;
    if (l < delta) {
        for (int idx = tid; idx < PLUP_; idx += 128) out[idx] = 0;
        return;
    }
    __shared__ float zc[R_], zp[R_];
    if (tid < R_) {
        zc[tid] = z[(size_t)row * R_ + tid];
        zp[tid] = z[(size_t)(row - delta) * R_ + tid];
    }
    __syncthreads();
    float vals[3];
    float ss = 0.f;
    #pragma unroll
    for (int t = 0; t < 3; ++t) {
        int idx = tid + t * 128;
        float val = 0.f;
        if (idx < PLU_) {
            int i = 0, rem = idx;
            while (rem >= 23 - i) { rem -= 23 - i; ++i; }
            int j = i + 1 + rem;
            val = zp[i] * zc[j] - zp[j] * zc[i];
        }
        vals[t] = val;
        ss += val * val;
    }
    #pragma unroll
    for (int off = 32; off > 0; off >>= 1) ss += __shfl_down(ss, off);
    __shared__ float wsum[2];
    if ((tid & 63) == 0) wsum[tid >> 6] = ss;
    __syncthreads();
    float inv = 1.0f / fmaxf(sqrtf(wsum[0] + wsum[1]), EPS_);
    #pragma unroll
    for (int t = 0; t < 3; ++t) {
        int idx = tid + t * 128;
        if (idx < PLUP_) out[idx] = (idx < PLU_) ? f2b(vals[t] * inv) : (ushort)0;
    }
}

// ---------------------------------------------------------------------------
static void mg128(int epi, const ushort* A, const ushort* W, const float* bias,
                  float* Cf, ushort* Cb, int M, int N, int K, hipStream_t s)
{
    dim3 grid(M / 128, (N + 127) / 128), block(256);
    if (epi == 1) mgemm128_k<1><<<grid, block, 0, s>>>(A, W, bias, Cf, Cb, M, N, K);
    else          mgemm128_k<4><<<grid, block, 0, s>>>(A, W, bias, Cf, Cb, M, N, K);
}

static void mg12864(int epi, const ushort* A, const ushort* W, const float* bias,
                    float* Cf, const ushort* hg, ushort* ub,
                    int M, int N, int K, hipStream_t s)
{
    dim3 grid(M / 128, N / 64), block(256);
    if (epi == 2)      mgemm12864_k<2><<<grid, block, 0, s>>>(A, W, bias, Cf, hg, ub, M, N, K);
    else if (epi == 3) mgemm12864_k<3><<<grid, block, 0, s>>>(A, W, bias, Cf, hg, ub, M, N, K);
    else               mgemm12864_k<5><<<grid, block, 0, s>>>(A, W, bias, Cf, hg, ub, M, N, K);
}

extern "C" void kernel_launch(void* const* d_in, const int* in_sizes, int n_in,
                              void* d_out, int out_size, void* d_ws, size_t ws_size,
                              hipStream_t stream)
{
    const int*   ids   = (const int*)d_in[0];
    const float* tok   = (const float*)d_in[1];
    const float* pos   = (const float*)d_in[2];
    const float* ln1w  = (const float*)d_in[3];
    const float* ln1b  = (const float*)d_in[4];
    const float* redw  = (const float*)d_in[5];
    const float* redb  = (const float*)d_in[6];
    const float* gp1w  = (const float*)d_in[7];
    const float* gp1b  = (const float*)d_in[8];
    const float* gp2w  = (const float*)d_in[9];
    const float* gp2b  = (const float*)d_in[10];
    const float* gatew = (const float*)d_in[11];
    const float* gateb = (const float*)d_in[12];
    const float* ln2w  = (const float*)d_in[13];
    const float* ln2b  = (const float*)d_in[14];
    const float* fc1w  = (const float*)d_in[15];
    const float* fc1b  = (const float*)d_in[16];
    const float* fc2w  = (const float*)d_in[17];
    const float* fc2b  = (const float*)d_in[18];
    const float* fnw   = (const float*)d_in[19];
    const float* fnb   = (const float*)d_in[20];
    float* out = (float*)d_out;

    const size_t MD = (size_t)M_ * D_;
    float* ws = (float*)d_ws;
    float* x = ws;                       // MD f32
    float* z = x + MD;                   // M_*R_ f32
    ushort* pb    = (ushort*)(z + (size_t)M_ * R_);       // 7*M_*288
    ushort* c1b   = pb + (size_t)7 * M_ * PLUP_;          // 7*M_*256
    ushort* crb   = c1b + (size_t)7 * M_ * DG_;           // M_*256
    ushort* hgb   = crb + (size_t)M_ * DG_;               // M_*1280
    ushort* h2b   = hgb + (size_t)M_ * 2 * D_;            // M_*640
    ushort* ffb   = h2b + MD;                             // M_*2560
    ushort* xnb   = ffb + (size_t)M_ * DF_;               // M_*640
    ushort* tokb  = xnb + MD;                             // V_*640
    ushort* wb    = tokb + (size_t)V_ * D_;               // WC_F2 (or x16)

    const size_t base_bytes = (size_t)((char*)wb - (char*)d_ws);
    const bool all_w = ws_size >= base_bytes + (size_t)NL_ * WC_F2 * 2;

    const int ELT_GRID = (M_ * D_ + 255) / 256;
    const int WC_GRID = (WC_F2 + 255) / 256;

    embed_k<<<ELT_GRID, 256, 0, stream>>>(ids, tok, pos, x);
    cvt_k<<<(V_ * D_ + 255) / 256, 256, 0, stream>>>(tok, tokb, V_ * D_);
    if (all_w)
        wconv_all_k<<<dim3(WC_GRID, NL_), 256, 0, stream>>>(gp1w, gp2w, gatew, fc1w, fc2w, wb);

    for (int l = 0; l < NL_; ++l) {
        const ushort* wbl = all_w ? wb + (size_t)l * WC_F2 : wb;
        if (!all_w)
            wconv_k<<<WC_GRID, 256, 0, stream>>>(
                gp1w + (size_t)l * DG_ * PLU_, gp2w + (size_t)l * D_ * DG_,
                gatew + (size_t)l * D_ * 2 * D_, fc1w + (size_t)l * DF_ * D_,
                fc2w + (size_t)l * D_ * DF_, wb);
        lnred_k<<<M_, 128, 0, stream>>>(x, ln1w + (size_t)l * D_, ln1b + (size_t)l * D_,
                                        redw + (size_t)l * R_ * D_, redb + (size_t)l * R_,
                                        hgb, z);
        plucker7_k<<<dim3(M_, 7), 128, 0, stream>>>(z, pb);
        mg128(1, pb, wbl, gp1b + (size_t)l * DG_, nullptr, c1b, 7 * M_, DG_, PLUP_, stream);
        credsum_k<<<(M_ * DG_ / 4 + 255) / 256, 256, 0, stream>>>(c1b, crb);
        // gp2 on M rows (linearity fusion): g -> bf16 into hgb[.,D..2D)
        mg12864(5, crb, wbl + WC_G1, gp2b + (size_t)l * D_, nullptr, hgb, hgb,
                M_, D_, DG_, stream);
        // gate fused with x-update; h,g read from bf16 hgb
        mg12864(2, hgb, wbl + WC_G2, gateb + (size_t)l * D_, x, hgb, nullptr,
                M_, D_, 2 * D_, stream);
        ln_k<<<M_, 128, 0, stream>>>(x, ln2w + (size_t)l * D_, ln2b + (size_t)l * D_,
                                     nullptr, h2b, D_);
        mg128(1, h2b, wbl + WC_GT, fc1b + (size_t)l * DF_, nullptr, ffb, M_, DF_, D_, stream);
        mg12864(3, ffb, wbl + WC_F1, fc2b + (size_t)l * D_, x, nullptr, nullptr,
                M_, D_, DF_, stream);
    }
    ln_k<<<M_, 128, 0, stream>>>(x, fnw, fnb, nullptr, xnb, D_);
    {   // lm_head: 256x128 tile + nontemporal stores
        dim3 grid(M_ / 256, (V_ + 127) / 128), block(512);
        mgemm256nt_k<<<grid, block, 0, stream>>>(xnb, tokb, out, M_, V_, D_);
    }
}